// Round 3
// baseline (647.747 us; speedup 1.0000x reference)
//
#include <hip/hip_runtime.h>

typedef unsigned short u16;
typedef __attribute__((ext_vector_type(8))) short short8;
typedef __attribute__((ext_vector_type(4))) float f32x4;

#define MFMA16(a,b,c) __builtin_amdgcn_mfma_f32_16x16x32_bf16(a,b,c,0,0,0)

// ---- problem constants ----
#define B_SZ   32768
#define HID_SZ 1024
#define NNODE  64
#define NB_PAIR (B_SZ*NNODE)           // 2097152
#define OUT_PROJ   327680
#define OUT_ENT    458752
#define OUT_ORTHO  458753

// ---- workspace byte offsets ----
#define OFF_SCAL   ((size_t)0)                         // float[128]; [127] = isfp32 flag
#define OFF_ADJ    ((size_t)512)                       // float[4096]
#define OFF_BEFF   (OFF_ADJ  + 4096u*4u)               // float[1024]
#define OFF_WEFF   (OFF_BEFF + 1024u*4u)               // u16[1024*64]
#define OFF_WCAT   (OFF_WEFF + 65536u*2u)              // u16[32*1024]
#define OFF_S1     (OFF_WCAT + 32768u*2u)              // float[512*3]
#define OFF_S2     (OFF_S1   + 512u*3u*4u)             // float[2048*2]
#define OFF_S2V    (OFF_S2   + 2048u*2u*4u)            // float[2048]
#define OFF_S3     (OFF_S2V  + 2048u*4u)               // float[1024*192]
#define OFF_S4     (OFF_S3   + 1024u*192u*4u)          // float[2048*2]
#define OFF_H      (OFF_S4   + 2048u*2u*4u)            // float[32768*8]
#define OFF_W01    (OFF_H    + (size_t)B_SZ*8u*4u)     // float[NB_PAIR*2]
#define OFF_XAGG   (OFF_W01  + (size_t)NB_PAIR*2u*4u)  // u16[NB_PAIR*16] (reused as xflat)
#define OFF_XPROC  (OFF_XAGG + (size_t)NB_PAIR*16u*2u) // u16[NB_PAIR*16]
#define OFF_CAN    (OFF_XPROC+ (size_t)NB_PAIR*16u*2u) // canonical bf16 inputs
#define NSTATS     (512*3 + 2048*2 + 2048 + 1024*192 + 2048*2)

// canonical element offsets (u16 units, from OFF_CAN)
#define CAN_X      0u
#define CAN_WEMB   2097152u
#define CAN_WREAD  (CAN_WEMB + 65536u)
#define CAN_SCW1   (CAN_WREAD + 10240u)
#define CAN_SMALL  (CAN_SCW1 + 8192u)
#define CAN_TOTAL  (CAN_SMALL + 11008u)
#define WS_NEEDED  (OFF_CAN + (size_t)CAN_TOTAL*2u)

__device__ __forceinline__ float bf2f(u16 u){
    unsigned v = ((unsigned)u) << 16;
    return __builtin_bit_cast(float, v);
}
__device__ __forceinline__ u16 f2bf(float f){
    unsigned u = __builtin_bit_cast(unsigned, f);
    u += 0x7FFFu + ((u >> 16) & 1u);           // RTN-even
    return (u16)(u >> 16);
}
__device__ __forceinline__ float sigm(float x){ return 1.f/(1.f + expf(-x)); }
__device__ __forceinline__ u16 conv_one(const void* src, int i, int isfp32){
    return isfp32 ? f2bf(((const float*)src)[i]) : ((const u16*)src)[i];
}
__device__ __forceinline__ void store_out(void* dout, int idx, float v, int isfp32){
    if (isfp32) ((float*)dout)[idx] = v;
    else        ((u16*)dout)[idx]   = f2bf(v);
}

// regulator: Linear(in_dim->16) -> LayerNorm -> *g+be -> tanh -> Linear(16->3) -> sigmoid
__device__ void run_regulator(const u16* w1, const u16* b1, const u16* g,
                              const u16* be, const u16* w2, const u16* b2,
                              const float* sig, int in_dim, float* out)
{
    float h[16];
    float mu = 0.f;
    for (int i = 0; i < 16; ++i){
        float a = bf2f(b1[i]);
        for (int j = 0; j < in_dim; ++j) a += sig[j]*bf2f(w1[i*in_dim + j]);
        h[i] = a; mu += a;
    }
    mu *= 0.0625f;
    float var = 0.f;
    for (int i = 0; i < 16; ++i){ float d = h[i]-mu; var += d*d; }
    var *= 0.0625f;
    float inv = 1.f / sqrtf(var + 1e-5f);
    for (int i = 0; i < 16; ++i){
        float hn = (h[i]-mu)*inv;
        h[i] = tanhf(hn*bf2f(g[i]) + bf2f(be[i]));
    }
    for (int c = 0; c < 3; ++c){
        float o = bf2f(b2[c]);
        for (int i = 0; i < 16; ++i) o += h[i]*bf2f(w2[c*16 + i]);
        out[c] = sigm(o);
    }
}

// KZ: zero stat buffers + scal
__global__ __launch_bounds__(256) void kz_zero(float* scal, float* stats)
{
    int i = blockIdx.x*256 + threadIdx.x;
    if (i < 128) scal[i] = 0.f;
    for (int j = i; j < NSTATS; j += gridDim.x*256) stats[j] = 0.f;
}

// KP: dtype probe. Even-indexed u16s of x: bf16 data -> sane exponents ~100%; fp32 -> ~20%.
__global__ __launch_bounds__(256) void kp_probe(const u16* xraw, float* scal)
{
    __shared__ int red[4];
    int tid = threadIdx.x, wave = tid>>6, lane = tid&63;
    int c = 0;
    #pragma unroll
    for (int j = 0; j < 4; ++j){
        u16 u = xraw[(tid*4 + j)*2];
        int e = (u >> 7) & 0xFF;
        if (u == 0 || (e >= 90 && e <= 140)) c++;
    }
    #pragma unroll
    for (int off = 32; off > 0; off >>= 1) c += __shfl_xor(c, off);
    if (lane == 0) red[wave] = c;
    __syncthreads();
    if (tid == 0){
        int tot = red[0]+red[1]+red[2]+red[3];   // of 1024
        scal[127] = (tot < 614) ? 1.0f : 0.0f;   // 1 => inputs are fp32
    }
}

// KCB: canonicalize the 4 big inputs to bf16
__global__ __launch_bounds__(256) void kc_big(const void* x, const void* wemb,
    const void* wread, const void* scw1, u16* can, const float* scal)
{
    int isfp32 = scal[127] != 0.f;
    int gid = blockIdx.x*256 + threadIdx.x, stride = gridDim.x*256;
    for (int i = gid; i < 2097152; i += stride) can[CAN_X + i]     = conv_one(x, i, isfp32);
    for (int i = gid; i < 65536;   i += stride) can[CAN_WEMB + i]  = conv_one(wemb, i, isfp32);
    for (int i = gid; i < 10240;   i += stride) can[CAN_WREAD + i] = conv_one(wread, i, isfp32);
    for (int i = gid; i < 8192;    i += stride) can[CAN_SCW1 + i]  = conv_one(scw1, i, isfp32);
}

// KCS: canonicalize 36 small inputs
struct SmallTab { const void* src[36]; int cnt[36]; int off[36]; };
__global__ __launch_bounds__(256) void kc_small(SmallTab t, u16* can, const float* scal)
{
    int isfp32 = scal[127] != 0.f;
    int gid = blockIdx.x*256 + threadIdx.x, stride = gridDim.x*256;
    for (int e = 0; e < 36; ++e){
        const void* s = t.src[e];
        u16* d = can + t.off[e];
        int n = t.cnt[e];
        for (int i = gid; i < n; i += stride) d[i] = conv_one(s, i, isfp32);
    }
}

// K0: Wcat[32][1024] = [W_read(10); sc_w1(8); zeros(14)]
__global__ __launch_bounds__(256) void k0_wcat(const u16* wread, const u16* scw1, u16* wcat)
{
    int idx = blockIdx.x*256 + threadIdx.x;
    int row = idx >> 10, k = idx & 1023;
    u16 v = 0;
    if (row < 10)      v = wread[row*1024 + k];
    else if (row < 18) v = scw1[(row-10)*1024 + k];
    wcat[idx] = v;
}

// K1: MFMA x@W_embed^T (no store); stats sum|xe+b|, x sum/sumsq
__global__ __launch_bounds__(256) void k1_embed(const u16* x, const u16* wemb,
                                                const u16* bemb, float* s1)
{
    __shared__ float red[12];
    int tid = threadIdx.x, wave = tid>>6, lane = tid&63;
    int m = lane&15, quad = lane>>4;
    int row = blockIdx.x*64 + wave*16 + m;
    const u16* xr = x + row*64 + quad*8;
    short8 a0 = *(const short8*)xr;
    short8 a1 = *(const short8*)(xr + 32);
    float sx = 0.f, sxx = 0.f;
    #pragma unroll
    for (int j = 0; j < 8; ++j){
        float f0 = bf2f((u16)a0[j]); sx += f0; sxx += f0*f0;
        float f1 = bf2f((u16)a1[j]); sx += f1; sxx += f1*f1;
    }
    float sabs = 0.f;
    for (int t = 0; t < 64; ++t){
        int col = t*16 + m;
        const u16* wr = wemb + col*64 + quad*8;
        short8 b0 = *(const short8*)wr;
        short8 b1 = *(const short8*)(wr + 32);
        f32x4 acc = {0.f,0.f,0.f,0.f};
        acc = MFMA16(a0, b0, acc);
        acc = MFMA16(a1, b1, acc);
        float bias = bf2f(bemb[col]);
        sabs += fabsf(acc[0]+bias) + fabsf(acc[1]+bias)
              + fabsf(acc[2]+bias) + fabsf(acc[3]+bias);
    }
    #pragma unroll
    for (int off = 32; off > 0; off >>= 1){
        sx   += __shfl_xor(sx, off);
        sxx  += __shfl_xor(sxx, off);
        sabs += __shfl_xor(sabs, off);
    }
    if (lane == 0){ red[wave*3] = sx; red[wave*3+1] = sxx; red[wave*3+2] = sabs; }
    __syncthreads();
    if (tid == 0){
        for (int k = 0; k < 3; ++k)
            s1[blockIdx.x*3 + k] = red[k] + red[3+k] + red[6+k] + red[9+k];
    }
}

// K2 (1 block): stats -> regulator pr -> pl0; build normalized adj
__global__ __launch_bounds__(256) void k2_adj(const u16* adjw, const u16* adjm,
    const u16* w1, const u16* b1, const u16* g, const u16* be, const u16* w2, const u16* b2,
    const float* s1, float* scal, float* adj)
{
    __shared__ double sred[256];
    __shared__ float raw[4096];
    __shared__ float rowsum[64];
    __shared__ float pl0s;
    int tid = threadIdx.x;
    double s=0, ss=0, sa=0;
    for (int i = tid; i < 512; i += 256){
        s += (double)s1[i*3]; ss += (double)s1[i*3+1]; sa += (double)s1[i*3+2];
    }
    double nq = 0;
    for (int i = tid; i < 4096; i += 256){ float f = bf2f(adjw[i]); nq += (double)(f*f); }
    sred[tid]=s;  __syncthreads(); if (tid==0){ for(int i=1;i<256;i++) s +=sred[i]; } __syncthreads();
    sred[tid]=ss; __syncthreads(); if (tid==0){ for(int i=1;i<256;i++) ss+=sred[i]; } __syncthreads();
    sred[tid]=sa; __syncthreads(); if (tid==0){ for(int i=1;i<256;i++) sa+=sred[i]; } __syncthreads();
    sred[tid]=nq; __syncthreads(); if (tid==0){ for(int i=1;i<256;i++) nq+=sred[i]; } __syncthreads();
    if (tid == 0){
        double nx = 2097152.0;
        float sg[3];
        sg[0] = (float)((ss - s*s/nx)/(nx - 1.0));
        sg[1] = (float)(sa / 33554432.0);
        sg[2] = sqrtf((float)nq);
        float o[3];
        run_regulator(w1,b1,g,be,w2,b2, sg, 3, o);
        scal[0] = o[0]; pl0s = o[0];
    }
    __syncthreads();
    float pl0 = pl0s;
    for (int i = tid; i < 4096; i += 256)
        raw[i] = sigm(bf2f(adjw[i])*pl0) * bf2f(adjm[i]);
    __syncthreads();
    if (tid < 64){
        float r = 0.f;
        for (int mc = 0; mc < 64; ++mc) r += raw[tid*64 + mc];
        rowsum[tid] = fmaxf(r, 1e-6f);
    }
    __syncthreads();
    for (int i = tid; i < 4096; i += 256) adj[i] = raw[i] / rowsum[i>>6];
}

// K2b: W_eff = adj-fold of W_embed
__global__ __launch_bounds__(256) void k2b_weff(const u16* wemb, const u16* bemb,
                                                const float* adj, u16* weff, float* beff)
{
    __shared__ float arow[64];
    int n = blockIdx.x, tid = threadIdx.x;
    if (tid < 64) arow[tid] = adj[n*64 + tid];
    __syncthreads();
    int k = tid & 63, dg = tid >> 6;
    for (int dd = 0; dd < 4; ++dd){
        int d = dg*4 + dd;
        float acc = 0.f;
        for (int mm = 0; mm < 64; ++mm)
            acc += arow[mm] * bf2f(wemb[(mm*16 + d)*64 + k]);
        weff[(n*16 + d)*64 + k] = f2bf(acc);
    }
    if (tid < 16){
        float acc = 0.f;
        for (int mm = 0; mm < 64; ++mm)
            acc += arow[mm] * bf2f(bemb[mm*16 + tid]);
        beff[n*16 + tid] = acc;
    }
}

// K3: MFMA x@W_eff^T + beff -> xagg + sum/sumsq stats
__global__ __launch_bounds__(256) void k3_agg(const u16* x, const u16* weff, const float* beff,
                                              u16* xagg, float* s2)
{
    __shared__ float red[8];
    int tid = threadIdx.x, wave = tid>>6, lane = tid&63;
    int m = lane&15, quad = lane>>4;
    int row0 = blockIdx.x*16;
    const u16* xr = x + (row0 + m)*64 + quad*8;
    short8 a0 = *(const short8*)xr;
    short8 a1 = *(const short8*)(xr + 32);
    float psum=0.f, pssq=0.f;
    for (int t = 0; t < 16; ++t){
        int col = wave*256 + t*16 + m;
        const u16* wr = weff + col*64 + quad*8;
        short8 b0 = *(const short8*)wr;
        short8 b1 = *(const short8*)(wr + 32);
        f32x4 acc = {0.f,0.f,0.f,0.f};
        acc = MFMA16(a0, b0, acc);
        acc = MFMA16(a1, b1, acc);
        float be = beff[col];
        #pragma unroll
        for (int r = 0; r < 4; ++r){
            float f = acc[r] + be;
            psum += f; pssq += f*f;
            xagg[(size_t)(row0 + quad*4 + r)*1024 + col] = f2bf(f);
        }
    }
    #pragma unroll
    for (int off = 32; off > 0; off >>= 1){
        psum += __shfl_xor(psum, off);
        pssq += __shfl_xor(pssq, off);
    }
    if (lane == 0){ red[wave] = psum; red[4+wave] = pssq; }
    __syncthreads();
    if (tid == 0){
        s2[blockIdx.x*2]   = red[0]+red[1]+red[2]+red[3];
        s2[blockIdx.x*2+1] = red[4]+red[5]+red[6]+red[7];
    }
}

// K3v: sum |x_agg @ V_slow^T|
__global__ __launch_bounds__(256) void k3v_absv(const u16* xagg, const u16* vslow, float* s2v)
{
    __shared__ float Vs[256];
    __shared__ float red[4];
    int tid = threadIdx.x, wave = tid>>6, lane = tid&63;
    Vs[tid] = bf2f(vslow[tid]);
    __syncthreads();
    float pabsv = 0.f;
    for (int it = 0; it < 4; ++it){
        size_t p = (size_t)blockIdx.x*1024 + it*256 + tid;
        const u16* xa = xagg + p*16;
        short8 u0 = *(const short8*)xa;
        short8 u1 = *(const short8*)(xa + 8);
        float xv[16];
        #pragma unroll
        for (int j = 0; j < 8; ++j){ xv[j] = bf2f((u16)u0[j]); xv[8+j] = bf2f((u16)u1[j]); }
        for (int i = 0; i < 16; ++i){
            float a = 0.f;
            #pragma unroll
            for (int d = 0; d < 16; ++d) a += Vs[i*16+d]*xv[d];
            pabsv += fabsf(a);
        }
    }
    #pragma unroll
    for (int off = 32; off > 0; off >>= 1) pabsv += __shfl_xor(pabsv, off);
    if (lane == 0) red[wave] = pabsv;
    __syncthreads();
    if (tid == 0) s2v[blockIdx.x] = red[0]+red[1]+red[2]+red[3];
}

// K3b: ctrl regulator
__global__ __launch_bounds__(256) void k3b_ctrl(const u16* wslow,
    const u16* w1, const u16* b1, const u16* g, const u16* be, const u16* w2, const u16* b2,
    const float* s2, const float* s2v, float* scal)
{
    __shared__ double sred[256];
    int tid = threadIdx.x;
    double s=0, ss=0, sv=0;
    for (int i = tid; i < 2048; i += 256){
        s += (double)s2[i*2]; ss += (double)s2[i*2+1]; sv += (double)s2v[i];
    }
    float wf = bf2f(wslow[tid]);
    double nq = (double)(wf*wf);
    sred[tid]=s;  __syncthreads(); if (tid==0){ for(int i=1;i<256;i++) s +=sred[i]; } __syncthreads();
    sred[tid]=ss; __syncthreads(); if (tid==0){ for(int i=1;i<256;i++) ss+=sred[i]; } __syncthreads();
    sred[tid]=sv; __syncthreads(); if (tid==0){ for(int i=1;i<256;i++) sv+=sred[i]; } __syncthreads();
    sred[tid]=nq; __syncthreads(); if (tid==0){ for(int i=1;i<256;i++) nq+=sred[i]; } __syncthreads();
    if (tid == 0){
        double M = 33554432.0;
        float sg[3];
        sg[0] = (float)((ss - s*s/M)/(M - 1.0));
        sg[1] = (float)(sv / M);
        sg[2] = sqrtf((float)nq);
        float o[3];
        run_regulator(w1,b1,g,be,w2,b2, sg, 3, o);
        scal[1] = o[0]; scal[2] = o[2];
    }
}

// K4: continuum + symbiotic softmax/entropy + per-node partials
__global__ __launch_bounds__(256) void k4_proc(const u16* xagg, const u16* vslow, const u16* wfast,
    const u16* gatew, const u16* gateb, const u16* wq, const u16* basis,
    const float* scal, u16* xproc, float* wbuf, float* s3)
{
    __shared__ float Vs[256], Wf[256], Wqs[256], gw[16], bas[32];
    __shared__ float part[768];
    int tid = threadIdx.x;
    Vs[tid]  = bf2f(vslow[tid]);
    Wf[tid]  = bf2f(wfast[tid]);
    Wqs[tid] = bf2f(wq[tid]);
    if (tid < 16) gw[tid]  = bf2f(gatew[tid]);
    if (tid < 32) bas[tid] = bf2f(basis[tid]);
    __syncthreads();
    float ctrl0 = scal[1], ctrl2 = scal[2];
    float gb = bf2f(gateb[0]);
    float psum=0.f, pssq=0.f, pent=0.f;
    for (int it = 0; it < 8; ++it){
        size_t p = (size_t)blockIdx.x*2048 + it*256 + tid;
        const u16* xa = xagg + p*16;
        short8 u0 = *(const short8*)xa;
        short8 u1 = *(const short8*)(xa + 8);
        float xv[16];
        #pragma unroll
        for (int j = 0; j < 8; ++j){ xv[j] = bf2f((u16)u0[j]); xv[8+j] = bf2f((u16)u1[j]); }
        float vv[16], ff[16];
        #pragma unroll
        for (int i = 0; i < 16; ++i){
            float a = 0.f, b = 0.f;
            #pragma unroll
            for (int d = 0; d < 16; ++d){ a += Vs[i*16+d]*xv[d]; b += Wf[i*16+d]*xv[d]; }
            vv[i] = a; ff[i] = b;
        }
        float gd = gb;
        #pragma unroll
        for (int i = 0; i < 16; ++i) gd += vv[i]*gw[i];
        float gate = sigm(gd)*ctrl0;
        float xp[16];
        #pragma unroll
        for (int i = 0; i < 16; ++i){
            xp[i] = gate*(vv[i] + ctrl2*ff[i]);
            psum += xp[i]; pssq += xp[i]*xp[i];
        }
        float q[16];
        #pragma unroll
        for (int i = 0; i < 16; ++i){
            float a = 0.f;
            #pragma unroll
            for (int d = 0; d < 16; ++d) a += Wqs[i*16+d]*xp[d];
            q[i] = a;
        }
        float l0 = 0.f, l1 = 0.f;
        #pragma unroll
        for (int i = 0; i < 16; ++i){ l0 += q[i]*bas[i]; l1 += q[i]*bas[16+i]; }
        l0 *= 0.25f; l1 *= 0.25f;
        float mx = fmaxf(l0, l1);
        float e0 = expf(l0-mx), e1 = expf(l1-mx);
        float is = 1.f/(e0+e1);
        float w0 = e0*is, w1 = e1*is;
        pent += -(w0*logf(w0+1e-8f) + w1*logf(w1+1e-8f));
        short8 o0, o1;
        #pragma unroll
        for (int j = 0; j < 8; ++j){ o0[j] = (short)f2bf(xp[j]); o1[j] = (short)f2bf(xp[8+j]); }
        *(short8*)(xproc + p*16)     = o0;
        *(short8*)(xproc + p*16 + 8) = o1;
        float2 wv; wv.x = w0; wv.y = w1;
        *(float2*)(wbuf + p*2) = wv;
    }
    part[tid] = psum; part[256+tid] = pssq; part[512+tid] = pent;
    __syncthreads();
    if (tid < 192){
        int stat = tid >> 6, n = tid & 63;
        const float* pp = &part[stat*256];
        s3[(size_t)blockIdx.x*192 + stat*64 + n] = pp[n] + pp[n+64] + pp[n+128] + pp[n+192];
    }
}

// K5: per-node regulator -> infl[64]; entropy(node63), ortho
__global__ __launch_bounds__(256) void k5_infl(const u16* basis,
    const u16* w1, const u16* b1, const u16* g, const u16* be, const u16* w2, const u16* b2,
    const float* s3, float* scal, void* dout)
{
    __shared__ double nst[192];
    int tid = threadIdx.x;
    int isfp32 = scal[127] != 0.f;
    if (tid < 192){
        double a = 0;
        for (int i = 0; i < 1024; ++i) a += (double)s3[(size_t)i*192 + tid];
        nst[tid] = a;
    }
    __syncthreads();
    if (tid < 64){
        int n = tid;
        double sum = nst[n], ssq = nst[64+n], ent = nst[128+n];
        double Mn = 524288.0;
        float varn = (float)((ssq - sum*sum/Mn)/(Mn - 1.0));
        float entm = (float)(ent / 32768.0);
        float b0[16], b1v[16];
        for (int d = 0; d < 16; ++d){ b0[d] = bf2f(basis[d]); b1v[d] = bf2f(basis[16+d]); }
        float g00=0.f, g01=0.f, g11=0.f;
        for (int d = 0; d < 16; ++d){ g00 += b0[d]*b0[d]; g01 += b0[d]*b1v[d]; g11 += b1v[d]*b1v[d]; }
        float ortho = sqrtf((g00-1.f)*(g00-1.f) + 2.f*g01*g01 + (g11-1.f)*(g11-1.f));
        float sg[3] = {varn, entm, ortho};
        float o[3];
        run_regulator(w1,b1,g,be,w2,b2, sg, 3, o);
        scal[4+n] = o[0];
        if (n == 63){ scal[68] = entm;  store_out(dout, OUT_ENT,   entm,  isfp32); }
        if (n == 0) { scal[69] = ortho; store_out(dout, OUT_ORTHO, ortho, isfp32); }
    }
}

// K6a: blend -> x_flat (into dead xagg region) + stats
__global__ __launch_bounds__(256) void k6a_blend(const u16* xproc, const float* wbuf,
    const u16* basis, const float* scal, u16* xflat, float* s4)
{
    __shared__ float infl_s[64], b0s[16], b1s[16];
    __shared__ float red[8];
    int tid = threadIdx.x, wave = tid>>6, lane = tid&63;
    if (tid < 64) infl_s[tid] = scal[4+tid];
    if (tid < 16){ b0s[tid] = bf2f(basis[tid]); b1s[tid] = bf2f(basis[16+tid]); }
    __syncthreads();
    float psum = 0.f, pssq = 0.f;
    for (int it = 0; it < 4; ++it){
        size_t p = (size_t)blockIdx.x*1024 + it*256 + tid;
        int n = (int)(p & 63);
        const u16* xa = xproc + p*16;
        short8 u0 = *(const short8*)xa;
        short8 u1 = *(const short8*)(xa + 8);
        float2 wv = *(const float2*)(wbuf + p*2);
        float fi = infl_s[n], om = 1.f - fi;
        short8 o0, o1;
        #pragma unroll
        for (int j = 0; j < 8; ++j){
            float xf0 = om*bf2f((u16)u0[j]) + fi*(wv.x*b0s[j]   + wv.y*b1s[j]);
            float xf1 = om*bf2f((u16)u1[j]) + fi*(wv.x*b0s[8+j] + wv.y*b1s[8+j]);
            psum += xf0 + xf1; pssq += xf0*xf0 + xf1*xf1;
            o0[j] = (short)f2bf(xf0); o1[j] = (short)f2bf(xf1);
        }
        *(short8*)(xflat + p*16)     = o0;
        *(short8*)(xflat + p*16 + 8) = o1;
    }
    #pragma unroll
    for (int off = 32; off > 0; off >>= 1){
        psum += __shfl_xor(psum, off);
        pssq += __shfl_xor(pssq, off);
    }
    if (lane == 0){ red[wave] = psum; red[4+wave] = pssq; }
    __syncthreads();
    if (tid == 0){
        s4[blockIdx.x*2]   = red[0]+red[1]+red[2]+red[3];
        s4[blockIdx.x*2+1] = red[4]+red[5]+red[6]+red[7];
    }
}

// K6b: MFMA x_flat @ Wcat^T -> logits + relu h
__global__ __launch_bounds__(256) void k6b_read(const u16* xflat, const u16* wcat,
    const u16* bread, const float* scal, void* dout, float* hbuf)
{
    __shared__ float brd[16];
    int tid = threadIdx.x;
    int isfp32 = scal[127] != 0.f;
    if (tid < 16) brd[tid] = (tid < 10) ? bf2f(bread[tid]) : 0.f;
    __syncthreads();
    int wave = tid>>6, lane = tid&63;
    int m = lane&15, quad = lane>>4;
    int row = blockIdx.x*64 + wave*16 + m;
    const u16* xrow = xflat + (size_t)row*1024;
    f32x4 acc0 = {0.f,0.f,0.f,0.f}, acc1 = {0.f,0.f,0.f,0.f};
    for (int kc = 0; kc < 1024; kc += 32){
        int kb = kc + quad*8;
        short8 af  = *(const short8*)(xrow + kb);
        short8 bb0 = *(const short8*)(wcat + m*1024 + kb);
        short8 bb1 = *(const short8*)(wcat + (16+m)*1024 + kb);
        acc0 = MFMA16(af, bb0, acc0);
        acc1 = MFMA16(af, bb1, acc1);
    }
    int rowbase = blockIdx.x*64 + wave*16 + quad*4;
    #pragma unroll
    for (int r = 0; r < 4; ++r){
        int rowg = rowbase + r;
        if (m < 10) store_out(dout, rowg*10 + m, acc0[r] + brd[m], isfp32);
        else        hbuf[rowg*8 + (m-10)] = fmaxf(acc0[r], 0.f);
        if (m < 2)  hbuf[rowg*8 + 6 + m]  = fmaxf(acc1[r], 0.f);
    }
}

// K7: gain regulator
__global__ __launch_bounds__(256) void k7_gain(
    const u16* w1, const u16* b1, const u16* g, const u16* be, const u16* w2, const u16* b2,
    const float* s4, float* scal)
{
    __shared__ double sred[256];
    int tid = threadIdx.x;
    double s=0, ss=0;
    for (int i = tid; i < 2048; i += 256){ s += (double)s4[i*2]; ss += (double)s4[i*2+1]; }
    sred[tid]=s;  __syncthreads(); if (tid==0){ for(int i=1;i<256;i++) s +=sred[i]; } __syncthreads();
    sred[tid]=ss; __syncthreads(); if (tid==0){ for(int i=1;i<256;i++) ss+=sred[i]; } __syncthreads();
    if (tid == 0){
        double M = 33554432.0;
        float sg[2];
        sg[0] = (float)((ss - s*s/M)/(M - 1.0));
        sg[1] = scal[68];
        float o[3];
        run_regulator(w1,b1,g,be,w2,b2, sg, 2, o);
        scal[3] = o[0];
    }
}

// K8: proj = (h @ sc_w2^T) * gain
__global__ __launch_bounds__(256) void k8_proj(const float* hbuf, const u16* scw2,
                                               const float* scal, void* dout)
{
    __shared__ float w2s[32];
    int tid = threadIdx.x;
    int isfp32 = scal[127] != 0.f;
    if (tid < 32) w2s[tid] = bf2f(scw2[tid]);
    __syncthreads();
    int b = blockIdx.x*256 + tid;
    float gain = scal[3];
    const float* h = hbuf + (size_t)b*8;
    float hv[8];
    #pragma unroll
    for (int k = 0; k < 8; ++k) hv[k] = h[k];
    #pragma unroll
    for (int i = 0; i < 4; ++i){
        float o = 0.f;
        #pragma unroll
        for (int k = 0; k < 8; ++k) o += hv[k]*w2s[i*8+k];
        store_out(dout, OUT_PROJ + b*4 + i, o*gain, isfp32);
    }
}

extern "C" void kernel_launch(void* const* d_in, const int* in_sizes, int n_in,
                              void* d_out, int out_size, void* d_ws, size_t ws_size,
                              hipStream_t stream)
{
    if (ws_size < WS_NEEDED) return;

    char* ws = (char*)d_ws;
    float* scal  = (float*)(ws + OFF_SCAL);
    float* adj   = (float*)(ws + OFF_ADJ);
    float* beff  = (float*)(ws + OFF_BEFF);
    u16*   weff  = (u16*)  (ws + OFF_WEFF);
    u16*   wcat  = (u16*)  (ws + OFF_WCAT);
    float* s1    = (float*)(ws + OFF_S1);
    float* s2    = (float*)(ws + OFF_S2);
    float* s2v   = (float*)(ws + OFF_S2V);
    float* s3    = (float*)(ws + OFF_S3);
    float* s4    = (float*)(ws + OFF_S4);
    float* hbuf  = (float*)(ws + OFF_H);
    float* wbuf  = (float*)(ws + OFF_W01);
    u16*   xagg  = (u16*)  (ws + OFF_XAGG);
    u16*   xproc = (u16*)  (ws + OFF_XPROC);
    u16*   can   = (u16*)  (ws + OFF_CAN);
    u16*   xflat = xagg;

    // canonical small-input table: indices into d_in, element counts
    static const int sidx[36] = {2,3,4,5,6,7,8,9,10,11,13,15,
        16,17,18,19,20,21, 22,23,24,25,26,27, 28,29,30,31,32,33, 34,35,36,37,38,39};
    static const int scnt[36] = {1024,4096,4096,256,256,16,1,256,32,256,32,10,
        48,16,16,16,48,3, 48,16,16,16,48,3, 48,16,16,16,48,3, 32,16,16,16,48,3};
    SmallTab t;
    const u16* canp[40];
    {
        int off = (int)CAN_SMALL;
        for (int j = 0; j < 36; ++j){
            t.src[j] = d_in[sidx[j]];
            t.cnt[j] = scnt[j];
            t.off[j] = off;
            canp[sidx[j]] = can + off;
            off += (scnt[j] + 7) & ~7;          // 16B-align each segment
        }
    }
    canp[0]  = can + CAN_X;
    canp[1]  = can + CAN_WEMB;
    canp[12] = can + CAN_SCW1;
    canp[14] = can + CAN_WREAD;

    const u16* pr_[6]; const u16* cr_[6]; const u16* sr_[6]; const u16* sc_[6];
    for (int i = 0; i < 6; ++i){
        pr_[i] = canp[16+i]; cr_[i] = canp[22+i];
        sr_[i] = canp[28+i]; sc_[i] = canp[34+i];
    }

    kz_zero <<<512, 256, 0, stream>>>(scal, s1);
    kp_probe<<<1,   256, 0, stream>>>((const u16*)d_in[0], scal);
    kc_big  <<<1024,256, 0, stream>>>(d_in[0], d_in[1], d_in[14], d_in[12], can, scal);
    kc_small<<<16,  256, 0, stream>>>(t, can, scal);
    k0_wcat <<<128, 256, 0, stream>>>(canp[14], canp[12], wcat);
    k1_embed<<<512, 256, 0, stream>>>(canp[0], canp[1], canp[2], s1);
    k2_adj  <<<1,   256, 0, stream>>>(canp[3], canp[4],
                 pr_[0],pr_[1],pr_[2],pr_[3],pr_[4],pr_[5], s1, scal, adj);
    k2b_weff<<<64,  256, 0, stream>>>(canp[1], canp[2], adj, weff, beff);
    k3_agg  <<<2048,256, 0, stream>>>(canp[0], weff, beff, xagg, s2);
    k3v_absv<<<2048,256, 0, stream>>>(xagg, canp[5], s2v);
    k3b_ctrl<<<1,   256, 0, stream>>>(canp[6],
                 cr_[0],cr_[1],cr_[2],cr_[3],cr_[4],cr_[5], s2, s2v, scal);
    k4_proc <<<1024,256, 0, stream>>>(xagg, canp[5], canp[9], canp[7], canp[8], canp[11],
                 canp[10], scal, xproc, wbuf, s3);
    k5_infl <<<1,   256, 0, stream>>>(canp[10],
                 sr_[0],sr_[1],sr_[2],sr_[3],sr_[4],sr_[5], s3, scal, d_out);
    k6a_blend<<<2048,256, 0, stream>>>(xproc, wbuf, canp[10], scal, xflat, s4);
    k6b_read<<<512, 256, 0, stream>>>(xflat, wcat, canp[15], scal, d_out, hbuf);
    k7_gain <<<1,   256, 0, stream>>>(
                 sc_[0],sc_[1],sc_[2],sc_[3],sc_[4],sc_[5], s4, scal);
    k8_proj <<<128, 256, 0, stream>>>(hbuf, canp[13], scal, d_out);
}

// Round 4
// 517.658 us; speedup vs baseline: 1.2513x; 1.2513x over previous
//
#include <hip/hip_runtime.h>

typedef unsigned short u16;
typedef __attribute__((ext_vector_type(8))) short short8;
typedef __attribute__((ext_vector_type(4))) float f32x4;

#define MFMA16(a,b,c) __builtin_amdgcn_mfma_f32_16x16x32_bf16(a,b,c,0,0,0)

// ---- problem constants ----
#define B_SZ   32768
#define NNODE  64
#define NB_PAIR (B_SZ*NNODE)           // 2097152
#define OUT_PROJ   327680
#define OUT_ENT    458752
#define OUT_ORTHO  458753

// ---- workspace byte offsets ----
#define OFF_SCAL   ((size_t)0)                         // float[128]; [127] = isfp32 flag
#define OFF_ADJ    ((size_t)512)                       // float[4096]
#define OFF_BEFF   (OFF_ADJ  + 4096u*4u)               // float[1024]
#define OFF_WEFF   (OFF_BEFF + 1024u*4u)               // u16[1024*64]
#define OFF_WCAT   (OFF_WEFF + 65536u*2u)              // u16[32*1024]
#define OFF_S1     (OFF_WCAT + 32768u*2u)              // float[512*3]
#define OFF_S2     (OFF_S1   + 512u*3u*4u)             // float[2048*2]
#define OFF_S2V    (OFF_S2   + 2048u*2u*4u)            // float[1024]
#define OFF_S3     (OFF_S2V  + 2048u*4u)               // float[512*192]
#define OFF_S4     (OFF_S3   + 1024u*192u*4u)          // float[512*2]
#define OFF_H      (OFF_S4   + 2048u*2u*4u)            // float[32768*8]
#define OFF_W01    (OFF_H    + (size_t)B_SZ*8u*4u)     // float[NB_PAIR*2]
#define OFF_XAGG   (OFF_W01  + (size_t)NB_PAIR*2u*4u)  // u16[NB_PAIR*16]
#define OFF_XPROC  (OFF_XAGG + (size_t)NB_PAIR*16u*2u) // u16[NB_PAIR*16]
#define OFF_CAN    (OFF_XPROC+ (size_t)NB_PAIR*16u*2u) // canonical bf16 inputs

// canonical element offsets (u16 units, from OFF_CAN)
#define CAN_X      0u
#define CAN_WEMB   2097152u
#define CAN_WREAD  (CAN_WEMB + 65536u)
#define CAN_SCW1   (CAN_WREAD + 10240u)
#define CAN_SMALL  (CAN_SCW1 + 8192u)
#define CAN_TOTAL  (CAN_SMALL + 11008u)
#define OFF_BEX    (((OFF_CAN + (size_t)CAN_TOTAL*2u) + 63u) & ~(size_t)63u)
#define WS_NEEDED  (OFF_BEX + 48u*16u*2u)

__device__ __forceinline__ float bf2f(u16 u){
    unsigned v = ((unsigned)u) << 16;
    return __builtin_bit_cast(float, v);
}
__device__ __forceinline__ u16 f2bf(float f){
    unsigned u = __builtin_bit_cast(unsigned, f);
    u += 0x7FFFu + ((u >> 16) & 1u);           // RTN-even
    return (u16)(u >> 16);
}
__device__ __forceinline__ float sigm(float x){ return 1.f/(1.f + expf(-x)); }
__device__ __forceinline__ u16 conv_one(const void* src, int i, int isfp32){
    return isfp32 ? f2bf(((const float*)src)[i]) : ((const u16*)src)[i];
}
__device__ __forceinline__ void store_out(void* dout, int idx, float v, int isfp32){
    if (isfp32) ((float*)dout)[idx] = v;
    else        ((u16*)dout)[idx]   = f2bf(v);
}
// butterfly block reduction (256 threads), all threads uniform
__device__ __forceinline__ double blk_red(double v, double* sred, int tid){
    #pragma unroll
    for (int off = 32; off > 0; off >>= 1) v += __shfl_xor(v, off);
    if ((tid & 63) == 0) sred[tid >> 6] = v;
    __syncthreads();
    double r = sred[0] + sred[1] + sred[2] + sred[3];
    __syncthreads();
    return r;
}

// regulator: Linear(in_dim->16) -> LayerNorm -> *g+be -> tanh -> Linear(16->3) -> sigmoid
__device__ void run_regulator(const u16* w1, const u16* b1, const u16* g,
                              const u16* be, const u16* w2, const u16* b2,
                              const float* sig, int in_dim, float* out)
{
    float h[16];
    float mu = 0.f;
    for (int i = 0; i < 16; ++i){
        float a = bf2f(b1[i]);
        for (int j = 0; j < in_dim; ++j) a += sig[j]*bf2f(w1[i*in_dim + j]);
        h[i] = a; mu += a;
    }
    mu *= 0.0625f;
    float var = 0.f;
    for (int i = 0; i < 16; ++i){ float d = h[i]-mu; var += d*d; }
    var *= 0.0625f;
    float inv = 1.f / sqrtf(var + 1e-5f);
    for (int i = 0; i < 16; ++i){
        float hn = (h[i]-mu)*inv;
        h[i] = tanhf(hn*bf2f(g[i]) + bf2f(be[i]));
    }
    for (int c = 0; c < 3; ++c){
        float o = bf2f(b2[c]);
        for (int i = 0; i < 16; ++i) o += h[i]*bf2f(w2[c*16 + i]);
        out[c] = sigm(o);
    }
}

// KP: dtype probe. Even-indexed u16s of x: bf16 data -> sane exponents ~100%; fp32 -> ~20%.
__global__ __launch_bounds__(256) void kp_probe(const u16* xraw, float* scal)
{
    __shared__ int red[4];
    int tid = threadIdx.x, wave = tid>>6, lane = tid&63;
    int c = 0;
    #pragma unroll
    for (int j = 0; j < 4; ++j){
        u16 u = xraw[(tid*4 + j)*2];
        int e = (u >> 7) & 0xFF;
        if (u == 0 || (e >= 90 && e <= 140)) c++;
    }
    #pragma unroll
    for (int off = 32; off > 0; off >>= 1) c += __shfl_xor(c, off);
    if (lane == 0) red[wave] = c;
    __syncthreads();
    if (tid == 0){
        int tot = red[0]+red[1]+red[2]+red[3];
        scal[127] = (tot < 614) ? 1.0f : 0.0f;   // 1 => fp32 inputs
    }
}

// KCB: canonicalize the 4 big inputs to bf16
__global__ __launch_bounds__(256) void kc_big(const void* x, const void* wemb,
    const void* wread, const void* scw1, u16* can, const float* scal)
{
    int isfp32 = scal[127] != 0.f;
    int gid = blockIdx.x*256 + threadIdx.x, stride = gridDim.x*256;
    for (int i = gid; i < 2097152; i += stride) can[CAN_X + i]     = conv_one(x, i, isfp32);
    for (int i = gid; i < 65536;   i += stride) can[CAN_WEMB + i]  = conv_one(wemb, i, isfp32);
    for (int i = gid; i < 10240;   i += stride) can[CAN_WREAD + i] = conv_one(wread, i, isfp32);
    for (int i = gid; i < 8192;    i += stride) can[CAN_SCW1 + i]  = conv_one(scw1, i, isfp32);
}

// KCS: canonicalize 36 small inputs
struct SmallTab { const void* src[36]; int cnt[36]; int off[36]; };
__global__ __launch_bounds__(256) void kc_small(SmallTab t, u16* can, const float* scal)
{
    int isfp32 = scal[127] != 0.f;
    int gid = blockIdx.x*256 + threadIdx.x, stride = gridDim.x*256;
    for (int e = 0; e < 36; ++e){
        const void* s = t.src[e];
        u16* d = can + t.off[e];
        int n = t.cnt[e];
        for (int i = gid; i < n; i += stride) d[i] = conv_one(s, i, isfp32);
    }
}

// K0: Wcat[32][1024] = [W_read(10); sc_w1(8); zeros(14)]
__global__ __launch_bounds__(256) void k0_wcat(const u16* wread, const u16* scw1, u16* wcat)
{
    int idx = blockIdx.x*256 + threadIdx.x;
    int row = idx >> 10, k = idx & 1023;
    u16 v = 0;
    if (row < 10)      v = wread[row*1024 + k];
    else if (row < 18) v = scw1[(row-10)*1024 + k];
    wcat[idx] = v;
}

// K3c0: Bex rows 0-32 + zero rows 35-47 (ctrl2-independent part)
__global__ __launch_bounds__(64) void k3c0(const u16* vslow, const u16* wfast,
                                           const u16* gatew, u16* bex)
{
    int r = threadIdx.x;
    if (r < 16)      for (int k = 0; k < 16; ++k) bex[r*16+k] = vslow[r*16+k];
    else if (r < 32) for (int k = 0; k < 16; ++k) bex[r*16+k] = wfast[(r-16)*16+k];
    else if (r == 32){
        for (int k = 0; k < 16; ++k){
            float a = 0.f;
            for (int i = 0; i < 16; ++i) a += bf2f(gatew[i])*bf2f(vslow[i*16+k]);
            bex[32*16+k] = f2bf(a);
        }
    }
    else if (r >= 35 && r < 48) for (int k = 0; k < 16; ++k) bex[r*16+k] = 0;
}

// K3c1: Bex rows 33,34 = e0,e1 (needs ctrl2)
__global__ __launch_bounds__(64) void k3c1(const u16* vslow, const u16* wfast,
    const u16* wq, const u16* basis, const float* scal, u16* bex)
{
    int tid = threadIdx.x;
    if (tid >= 32) return;
    int a = tid >> 4, k = tid & 15;
    float ctrl2 = scal[2];
    float e = 0.f;
    for (int d = 0; d < 16; ++d){
        float bq = 0.f;
        for (int j = 0; j < 16; ++j) bq += bf2f(basis[a*16+j])*bf2f(wq[j*16+d]);
        e += bq*(bf2f(vslow[d*16+k]) + ctrl2*bf2f(wfast[d*16+k]));
    }
    bex[(33+a)*16+k] = f2bf(0.25f*e);
}

// K1: MFMA x@W_embed^T (no store); stats sum|xe+b|, x sum/sumsq
__global__ __launch_bounds__(256) void k1_embed(const u16* x, const u16* wemb,
                                                const u16* bemb, float* s1)
{
    __shared__ float red[12];
    int tid = threadIdx.x, wave = tid>>6, lane = tid&63;
    int m = lane&15, quad = lane>>4;
    int row = blockIdx.x*64 + wave*16 + m;
    const u16* xr = x + row*64 + quad*8;
    short8 a0 = *(const short8*)xr;
    short8 a1 = *(const short8*)(xr + 32);
    float sx = 0.f, sxx = 0.f;
    #pragma unroll
    for (int j = 0; j < 8; ++j){
        float f0 = bf2f((u16)a0[j]); sx += f0; sxx += f0*f0;
        float f1 = bf2f((u16)a1[j]); sx += f1; sxx += f1*f1;
    }
    float sabs = 0.f;
    for (int t = 0; t < 64; ++t){
        int col = t*16 + m;
        const u16* wr = wemb + col*64 + quad*8;
        short8 b0 = *(const short8*)wr;
        short8 b1 = *(const short8*)(wr + 32);
        f32x4 acc = {0.f,0.f,0.f,0.f};
        acc = MFMA16(a0, b0, acc);
        acc = MFMA16(a1, b1, acc);
        float bias = bf2f(bemb[col]);
        sabs += fabsf(acc[0]+bias) + fabsf(acc[1]+bias)
              + fabsf(acc[2]+bias) + fabsf(acc[3]+bias);
    }
    #pragma unroll
    for (int off = 32; off > 0; off >>= 1){
        sx   += __shfl_xor(sx, off);
        sxx  += __shfl_xor(sxx, off);
        sabs += __shfl_xor(sabs, off);
    }
    if (lane == 0){ red[wave*3] = sx; red[wave*3+1] = sxx; red[wave*3+2] = sabs; }
    __syncthreads();
    if (tid == 0){
        for (int k = 0; k < 3; ++k)
            s1[blockIdx.x*3 + k] = red[k] + red[3+k] + red[6+k] + red[9+k];
    }
}

// K2 (1 block): stats -> regulator pr -> pl0; build normalized adj
__global__ __launch_bounds__(256) void k2_adj(const u16* adjw, const u16* adjm,
    const u16* w1, const u16* b1, const u16* g, const u16* be, const u16* w2, const u16* b2,
    const float* s1, float* scal, float* adj)
{
    __shared__ double sred[4];
    __shared__ float raw[4096];
    __shared__ float rowsum[64];
    __shared__ float pl0s;
    int tid = threadIdx.x;
    double s=0, ss=0, sa=0;
    for (int i = tid; i < 512; i += 256){
        s += (double)s1[i*3]; ss += (double)s1[i*3+1]; sa += (double)s1[i*3+2];
    }
    double nq = 0;
    for (int i = tid; i < 4096; i += 256){ float f = bf2f(adjw[i]); nq += (double)(f*f); }
    double S  = blk_red(s,  sred, tid);
    double SS = blk_red(ss, sred, tid);
    double SA = blk_red(sa, sred, tid);
    double NQ = blk_red(nq, sred, tid);
    if (tid == 0){
        double nx = 2097152.0;
        float sg[3];
        sg[0] = (float)((SS - S*S/nx)/(nx - 1.0));
        sg[1] = (float)(SA / 33554432.0);
        sg[2] = sqrtf((float)NQ);
        float o[3];
        run_regulator(w1,b1,g,be,w2,b2, sg, 3, o);
        scal[0] = o[0]; pl0s = o[0];
    }
    __syncthreads();
    float pl0 = pl0s;
    for (int i = tid; i < 4096; i += 256)
        raw[i] = sigm(bf2f(adjw[i])*pl0) * bf2f(adjm[i]);
    __syncthreads();
    if (tid < 64){
        float r = 0.f;
        for (int mc = 0; mc < 64; ++mc) r += raw[tid*64 + mc];
        rowsum[tid] = fmaxf(r, 1e-6f);
    }
    __syncthreads();
    for (int i = tid; i < 4096; i += 256) adj[i] = raw[i] / rowsum[i>>6];
}

// K2b: W_eff = adj-fold of W_embed
__global__ __launch_bounds__(256) void k2b_weff(const u16* wemb, const u16* bemb,
                                                const float* adj, u16* weff, float* beff)
{
    __shared__ float arow[64];
    int n = blockIdx.x, tid = threadIdx.x;
    if (tid < 64) arow[tid] = adj[n*64 + tid];
    __syncthreads();
    int k = tid & 63, dg = tid >> 6;
    for (int dd = 0; dd < 4; ++dd){
        int d = dg*4 + dd;
        float acc = 0.f;
        for (int mm = 0; mm < 64; ++mm)
            acc += arow[mm] * bf2f(wemb[(mm*16 + d)*64 + k]);
        weff[(n*16 + d)*64 + k] = f2bf(acc);
    }
    if (tid < 16){
        float acc = 0.f;
        for (int mm = 0; mm < 64; ++mm)
            acc += arow[mm] * bf2f(bemb[mm*16 + tid]);
        beff[n*16 + tid] = acc;
    }
}

// K3: MFMA x@W_eff^T + beff -> xagg + sum/sumsq stats
__global__ __launch_bounds__(256) void k3_agg(const u16* x, const u16* weff, const float* beff,
                                              u16* xagg, float* s2)
{
    __shared__ float red[8];
    int tid = threadIdx.x, wave = tid>>6, lane = tid&63;
    int m = lane&15, quad = lane>>4;
    int row0 = blockIdx.x*16;
    const u16* xr = x + (row0 + m)*64 + quad*8;
    short8 a0 = *(const short8*)xr;
    short8 a1 = *(const short8*)(xr + 32);
    float psum=0.f, pssq=0.f;
    for (int t = 0; t < 16; ++t){
        int col = wave*256 + t*16 + m;
        const u16* wr = weff + col*64 + quad*8;
        short8 b0 = *(const short8*)wr;
        short8 b1 = *(const short8*)(wr + 32);
        f32x4 acc = {0.f,0.f,0.f,0.f};
        acc = MFMA16(a0, b0, acc);
        acc = MFMA16(a1, b1, acc);
        float be = beff[col];
        #pragma unroll
        for (int r = 0; r < 4; ++r){
            float f = acc[r] + be;
            psum += f; pssq += f*f;
            xagg[(size_t)(row0 + quad*4 + r)*1024 + col] = f2bf(f);
        }
    }
    #pragma unroll
    for (int off = 32; off > 0; off >>= 1){
        psum += __shfl_xor(psum, off);
        pssq += __shfl_xor(pssq, off);
    }
    if (lane == 0){ red[wave] = psum; red[4+wave] = pssq; }
    __syncthreads();
    if (tid == 0){
        s2[blockIdx.x*2]   = red[0]+red[1]+red[2]+red[3];
        s2[blockIdx.x*2+1] = red[4]+red[5]+red[6]+red[7];
    }
}

// K3v: sum |x_agg @ V_slow^T| via MFMA (Bex rows 0-15). grid 1024 x 4 waves x 32 iters.
__global__ __launch_bounds__(256) void k3v_absv(const u16* xagg, const u16* bex, float* s2v)
{
    __shared__ float red[4];
    int tid = threadIdx.x, wave = tid>>6, lane = tid&63;
    int col = lane&15, quad = lane>>4;
    short8 z8 = {0,0,0,0,0,0,0,0};
    short8 b0 = z8;
    if (quad < 2) b0 = *(const short8*)(bex + col*16 + quad*8);
    float pabsv = 0.f;
    size_t wbase = ((size_t)blockIdx.x*4 + wave)*512;
    for (int it = 0; it < 32; ++it){
        size_t p0 = wbase + (size_t)it*16;
        short8 a = z8;
        if (quad < 2) a = *(const short8*)(xagg + (p0 + col)*16 + quad*8);
        f32x4 zc = {0.f,0.f,0.f,0.f};
        f32x4 c = MFMA16(a, b0, zc);
        pabsv += fabsf(c[0]) + fabsf(c[1]) + fabsf(c[2]) + fabsf(c[3]);
    }
    #pragma unroll
    for (int off = 32; off > 0; off >>= 1) pabsv += __shfl_xor(pabsv, off);
    if (lane == 0) red[wave] = pabsv;
    __syncthreads();
    if (tid == 0) s2v[blockIdx.x] = red[0]+red[1]+red[2]+red[3];
}

// K3b: ctrl regulator
__global__ __launch_bounds__(256) void k3b_ctrl(const u16* wslow,
    const u16* w1, const u16* b1, const u16* g, const u16* be, const u16* w2, const u16* b2,
    const float* s2, const float* s2v, float* scal)
{
    __shared__ double sred[4];
    int tid = threadIdx.x;
    double s=0, ss=0, sv=0;
    for (int i = tid; i < 2048; i += 256){
        s += (double)s2[i*2]; ss += (double)s2[i*2+1];
    }
    for (int i = tid; i < 1024; i += 256) sv += (double)s2v[i];
    float wf = bf2f(wslow[tid]);
    double nq = (double)(wf*wf);
    double S  = blk_red(s,  sred, tid);
    double SS = blk_red(ss, sred, tid);
    double SV = blk_red(sv, sred, tid);
    double NQ = blk_red(nq, sred, tid);
    if (tid == 0){
        double M = 33554432.0;
        float sg[3];
        sg[0] = (float)((SS - S*S/M)/(M - 1.0));
        sg[1] = (float)(SV / M);
        sg[2] = sqrtf((float)NQ);
        float o[3];
        run_regulator(w1,b1,g,be,w2,b2, sg, 3, o);
        scal[1] = o[0]; scal[2] = o[2];
    }
}

// K4: MFMA continuum+symbiotic. grid 512 x 4 waves x 64 iters x 16 pairs.
// Bex: rows 0-15 V, 16-31 Wf, 32 gv, 33 e0, 34 e1 (e includes 1/scale and ctrl2).
__global__ __launch_bounds__(256) void k4_proc(const u16* xagg, const u16* bex,
    const u16* gateb, const float* scal, u16* xproc, float* wbuf, float* s3)
{
    __shared__ float part[4][192];
    int tid = threadIdx.x, wave = tid>>6, lane = tid&63;
    int col = lane & 15, quad = lane >> 4;
    short8 z8 = {0,0,0,0,0,0,0,0};
    short8 b0 = z8, b1 = z8, b2 = z8;
    if (quad < 2){
        b0 = *(const short8*)(bex + col*16      + quad*8);
        b1 = *(const short8*)(bex + (16+col)*16 + quad*8);
        b2 = *(const short8*)(bex + (32+col)*16 + quad*8);
    }
    float ctrl0 = scal[1], ctrl2 = scal[2];
    float gb = bf2f(gateb[0]);
    float psum[4][4], pssq[4][4], pent[4][4];
    #pragma unroll
    for (int g = 0; g < 4; ++g)
    #pragma unroll
    for (int r = 0; r < 4; ++r){ psum[g][r]=0.f; pssq[g][r]=0.f; pent[g][r]=0.f; }
    size_t wbase = ((size_t)blockIdx.x*4 + wave)*1024;
    for (int it2 = 0; it2 < 16; ++it2){
        #pragma unroll
        for (int g = 0; g < 4; ++g){
            size_t p0 = wbase + (size_t)(it2*4 + g)*16;
            short8 a = z8;
            if (quad < 2) a = *(const short8*)(xagg + (p0 + col)*16 + quad*8);
            f32x4 zc = {0.f,0.f,0.f,0.f};
            f32x4 c0 = MFMA16(a, b0, zc);
            f32x4 c1 = MFMA16(a, b1, zc);
            f32x4 c2 = MFMA16(a, b2, zc);
            int grp = lane & 48;
            #pragma unroll
            for (int r = 0; r < 4; ++r){
                float gd  = __shfl(c2[r], grp);
                float e0d = __shfl(c2[r], grp+1);
                float e1d = __shfl(c2[r], grp+2);
                float gate = sigm(gd + gb) * ctrl0;
                float l0 = gate * e0d, l1 = gate * e1d;
                float mx = fmaxf(l0, l1);
                float ex0 = expf(l0-mx), ex1 = expf(l1-mx);
                float inv = 1.f/(ex0+ex1);
                float w0 = ex0*inv, w1 = ex1*inv;
                float entr = -(w0*logf(w0+1e-8f) + w1*logf(w1+1e-8f));
                float xp = gate*(c0[r] + ctrl2*c1[r]);
                psum[g][r] += xp; pssq[g][r] += xp*xp; pent[g][r] += entr;
                size_t pr = p0 + (size_t)(quad*4 + r);
                xproc[pr*16 + col] = f2bf(xp);
                if (col == 0){
                    float2 wv; wv.x = w0; wv.y = w1;
                    *(float2*)(wbuf + pr*2) = wv;
                }
            }
        }
    }
    #pragma unroll
    for (int g = 0; g < 4; ++g)
    #pragma unroll
    for (int r = 0; r < 4; ++r){
        float a = psum[g][r], b = pssq[g][r], c = pent[g][r];
        #pragma unroll
        for (int off = 1; off < 16; off <<= 1){
            a += __shfl_xor(a, off);
            b += __shfl_xor(b, off);
            c += __shfl_xor(c, off);
        }
        if (col == 0){
            int n = g*16 + quad*4 + r;
            part[wave][n]       = a;
            part[wave][64 + n]  = b;
            part[wave][128 + n] = c * 0.0625f;   // each of 16 lanes added full row entropy
        }
    }
    __syncthreads();
    if (tid < 192)
        s3[(size_t)blockIdx.x*192 + tid] =
            part[0][tid] + part[1][tid] + part[2][tid] + part[3][tid];
}

// K5: per-node regulator -> infl[64]; entropy(node63), ortho
__global__ __launch_bounds__(256) void k5_infl(const u16* basis,
    const u16* w1, const u16* b1, const u16* g, const u16* be, const u16* w2, const u16* b2,
    const float* s3, float* scal, void* dout)
{
    __shared__ double nst[192];
    int tid = threadIdx.x;
    int isfp32 = scal[127] != 0.f;
    if (tid < 192){
        double a = 0;
        for (int i = 0; i < 512; ++i) a += (double)s3[(size_t)i*192 + tid];
        nst[tid] = a;
    }
    __syncthreads();
    if (tid < 64){
        int n = tid;
        double sum = nst[n], ssq = nst[64+n], ent = nst[128+n];
        double Mn = 524288.0;
        float varn = (float)((ssq - sum*sum/Mn)/(Mn - 1.0));
        float entm = (float)(ent / 32768.0);
        float b0[16], b1v[16];
        for (int d = 0; d < 16; ++d){ b0[d] = bf2f(basis[d]); b1v[d] = bf2f(basis[16+d]); }
        float g00=0.f, g01=0.f, g11=0.f;
        for (int d = 0; d < 16; ++d){ g00 += b0[d]*b0[d]; g01 += b0[d]*b1v[d]; g11 += b1v[d]*b1v[d]; }
        float ortho = sqrtf((g00-1.f)*(g00-1.f) + 2.f*g01*g01 + (g11-1.f)*(g11-1.f));
        float sg[3] = {varn, entm, ortho};
        float o[3];
        run_regulator(w1,b1,g,be,w2,b2, sg, 3, o);
        scal[4+n] = o[0];
        if (n == 63){ scal[68] = entm;  store_out(dout, OUT_ENT,   entm,  isfp32); }
        if (n == 0) { scal[69] = ortho; store_out(dout, OUT_ORTHO, ortho, isfp32); }
    }
}

// K6: blend-on-load + MFMA GEMM [B x 1024] @ Wcat^T -> logits, relu h, x_flat stats.
__global__ __launch_bounds__(256) void k6_read(const u16* xproc, const float* wbuf, const u16* wcat,
    const u16* basis, const u16* bread, const float* scal,
    void* dout, float* hbuf, float* s4)
{
    __shared__ float infl_s[64], b0s[16], b1s[16], brd[16];
    __shared__ float red[8];
    int tid = threadIdx.x;
    int isfp32 = scal[127] != 0.f;
    if (tid < 64) infl_s[tid] = scal[4+tid];
    if (tid < 16){
        b0s[tid] = bf2f(basis[tid]);
        b1s[tid] = bf2f(basis[16+tid]);
        brd[tid] = (tid < 10) ? bf2f(bread[tid]) : 0.f;
    }
    __syncthreads();
    int wave = tid>>6, lane = tid&63;
    int m = lane&15, quad = lane>>4;
    int row = blockIdx.x*64 + wave*16 + m;
    const u16* xrow = xproc + (size_t)row*1024;
    f32x4 acc0 = {0.f,0.f,0.f,0.f}, acc1 = {0.f,0.f,0.f,0.f};
    float psum = 0.f, pssq = 0.f;
    for (int kc = 0; kc < 1024; kc += 32){
        int kb = kc + quad*8;
        int n  = kb >> 4;
        int d0 = kb & 15;
        short8 xp = *(const short8*)(xrow + kb);
        float2 wv = *(const float2*)(wbuf + ((size_t)row*64 + n)*2);
        float fi = infl_s[n], om = 1.f - fi;
        short8 af;
        #pragma unroll
        for (int j = 0; j < 8; ++j){
            int d = d0 + j;
            float xf = om*bf2f((u16)xp[j]) + fi*(wv.x*b0s[d] + wv.y*b1s[d]);
            psum += xf; pssq += xf*xf;
            af[j] = (short)f2bf(xf);
        }
        short8 bb0 = *(const short8*)(wcat + m*1024 + kb);
        short8 bb1 = *(const short8*)(wcat + (16+m)*1024 + kb);
        acc0 = MFMA16(af, bb0, acc0);
        acc1 = MFMA16(af, bb1, acc1);
    }
    int rowbase = blockIdx.x*64 + wave*16 + quad*4;
    #pragma unroll
    for (int r = 0; r < 4; ++r){
        int rowg = rowbase + r;
        if (m < 10) store_out(dout, rowg*10 + m, acc0[r] + brd[m], isfp32);
        else        hbuf[rowg*8 + (m-10)] = fmaxf(acc0[r], 0.f);
        if (m < 2)  hbuf[rowg*8 + 6 + m]  = fmaxf(acc1[r], 0.f);
    }
    #pragma unroll
    for (int off = 32; off > 0; off >>= 1){
        psum += __shfl_xor(psum, off);
        pssq += __shfl_xor(pssq, off);
    }
    if (lane == 0){ red[wave] = psum; red[4+wave] = pssq; }
    __syncthreads();
    if (tid == 0){
        s4[blockIdx.x*2]   = red[0]+red[1]+red[2]+red[3];
        s4[blockIdx.x*2+1] = red[4]+red[5]+red[6]+red[7];
    }
}

// K7: gain regulator
__global__ __launch_bounds__(256) void k7_gain(
    const u16* w1, const u16* b1, const u16* g, const u16* be, const u16* w2, const u16* b2,
    const float* s4, float* scal)
{
    __shared__ double sred[4];
    int tid = threadIdx.x;
    double s=0, ss=0;
    for (int i = tid; i < 512; i += 256){ s += (double)s4[i*2]; ss += (double)s4[i*2+1]; }
    double S  = blk_red(s,  sred, tid);
    double SS = blk_red(ss, sred, tid);
    if (tid == 0){
        double M = 33554432.0;
        float sg[2];
        sg[0] = (float)((SS - S*S/M)/(M - 1.0));
        sg[1] = scal[68];
        float o[3];
        run_regulator(w1,b1,g,be,w2,b2, sg, 2, o);
        scal[3] = o[0];
    }
}

// K8: proj = (h @ sc_w2^T) * gain
__global__ __launch_bounds__(256) void k8_proj(const float* hbuf, const u16* scw2,
                                               const float* scal, void* dout)
{
    __shared__ float w2s[32];
    int tid = threadIdx.x;
    int isfp32 = scal[127] != 0.f;
    if (tid < 32) w2s[tid] = bf2f(scw2[tid]);
    __syncthreads();
    int b = blockIdx.x*256 + tid;
    float gain = scal[3];
    const float* h = hbuf + (size_t)b*8;
    float hv[8];
    #pragma unroll
    for (int k = 0; k < 8; ++k) hv[k] = h[k];
    #pragma unroll
    for (int i = 0; i < 4; ++i){
        float o = 0.f;
        #pragma unroll
        for (int k = 0; k < 8; ++k) o += hv[k]*w2s[i*8+k];
        store_out(dout, OUT_PROJ + b*4 + i, o*gain, isfp32);
    }
}

extern "C" void kernel_launch(void* const* d_in, const int* in_sizes, int n_in,
                              void* d_out, int out_size, void* d_ws, size_t ws_size,
                              hipStream_t stream)
{
    if (ws_size < WS_NEEDED) return;

    char* ws = (char*)d_ws;
    float* scal  = (float*)(ws + OFF_SCAL);
    float* adj   = (float*)(ws + OFF_ADJ);
    float* beff  = (float*)(ws + OFF_BEFF);
    u16*   weff  = (u16*)  (ws + OFF_WEFF);
    u16*   wcat  = (u16*)  (ws + OFF_WCAT);
    float* s1    = (float*)(ws + OFF_S1);
    float* s2    = (float*)(ws + OFF_S2);
    float* s2v   = (float*)(ws + OFF_S2V);
    float* s3    = (float*)(ws + OFF_S3);
    float* s4    = (float*)(ws + OFF_S4);
    float* hbuf  = (float*)(ws + OFF_H);
    float* wbuf  = (float*)(ws + OFF_W01);
    u16*   xagg  = (u16*)  (ws + OFF_XAGG);
    u16*   xproc = (u16*)  (ws + OFF_XPROC);
    u16*   can   = (u16*)  (ws + OFF_CAN);
    u16*   bex   = (u16*)  (ws + OFF_BEX);

    static const int sidx[36] = {2,3,4,5,6,7,8,9,10,11,13,15,
        16,17,18,19,20,21, 22,23,24,25,26,27, 28,29,30,31,32,33, 34,35,36,37,38,39};
    static const int scnt[36] = {1024,4096,4096,256,256,16,1,256,32,256,32,10,
        48,16,16,16,48,3, 48,16,16,16,48,3, 48,16,16,16,48,3, 32,16,16,16,48,3};
    SmallTab t;
    const u16* canp[40];
    {
        int off = (int)CAN_SMALL;
        for (int j = 0; j < 36; ++j){
            t.src[j] = d_in[sidx[j]];
            t.cnt[j] = scnt[j];
            t.off[j] = off;
            canp[sidx[j]] = can + off;
            off += (scnt[j] + 7) & ~7;
        }
    }
    canp[0]  = can + CAN_X;
    canp[1]  = can + CAN_WEMB;
    canp[12] = can + CAN_SCW1;
    canp[14] = can + CAN_WREAD;

    const u16* pr_[6]; const u16* cr_[6]; const u16* sr_[6]; const u16* sc_[6];
    for (int i = 0; i < 6; ++i){
        pr_[i] = canp[16+i]; cr_[i] = canp[22+i];
        sr_[i] = canp[28+i]; sc_[i] = canp[34+i];
    }

    kp_probe<<<1,   256, 0, stream>>>((const u16*)d_in[0], scal);
    kc_big  <<<1024,256, 0, stream>>>(d_in[0], d_in[1], d_in[14], d_in[12], can, scal);
    kc_small<<<16,  256, 0, stream>>>(t, can, scal);
    k0_wcat <<<128, 256, 0, stream>>>(canp[14], canp[12], wcat);
    k3c0    <<<1,   64,  0, stream>>>(canp[5], canp[9], canp[7], bex);
    k1_embed<<<512, 256, 0, stream>>>(canp[0], canp[1], canp[2], s1);
    k2_adj  <<<1,   256, 0, stream>>>(canp[3], canp[4],
                 pr_[0],pr_[1],pr_[2],pr_[3],pr_[4],pr_[5], s1, scal, adj);
    k2b_weff<<<64,  256, 0, stream>>>(canp[1], canp[2], adj, weff, beff);
    k3_agg  <<<2048,256, 0, stream>>>(canp[0], weff, beff, xagg, s2);
    k3v_absv<<<1024,256, 0, stream>>>(xagg, bex, s2v);
    k3b_ctrl<<<1,   256, 0, stream>>>(canp[6],
                 cr_[0],cr_[1],cr_[2],cr_[3],cr_[4],cr_[5], s2, s2v, scal);
    k3c1    <<<1,   64,  0, stream>>>(canp[5], canp[9], canp[11], canp[10], scal, bex);
    k4_proc <<<512, 256, 0, stream>>>(xagg, bex, canp[8], scal, xproc, wbuf, s3);
    k5_infl <<<1,   256, 0, stream>>>(canp[10],
                 sr_[0],sr_[1],sr_[2],sr_[3],sr_[4],sr_[5], s3, scal, d_out);
    k6_read <<<512, 256, 0, stream>>>(xproc, wbuf, wcat, canp[10], canp[15], scal,
                 d_out, hbuf, s4);
    k7_gain <<<1,   256, 0, stream>>>(
                 sc_[0],sc_[1],sc_[2],sc_[3],sc_[4],sc_[5], s4, scal);
    k8_proj <<<128, 256, 0, stream>>>(hbuf, canp[13], scal, d_out);
}

// Round 5
// 449.201 us; speedup vs baseline: 1.4420x; 1.1524x over previous
//
#include <hip/hip_runtime.h>

typedef unsigned short u16;
typedef __attribute__((ext_vector_type(8))) short short8;
typedef __attribute__((ext_vector_type(4))) float f32x4;

#define MFMA16(a,b,c) __builtin_amdgcn_mfma_f32_16x16x32_bf16(a,b,c,0,0,0)

// ---- problem constants ----
#define B_SZ   32768
#define NNODE  64
#define NB_PAIR (B_SZ*NNODE)           // 2097152
#define OUT_PROJ   327680
#define OUT_ENT    458752
#define OUT_ORTHO  458753

// ---- workspace byte offsets ----
#define OFF_SCAL   ((size_t)0)                         // float[128]; [127] = isfp32 flag
#define OFF_ADJ    ((size_t)512)                       // float[4096]
#define OFF_BEFF   (OFF_ADJ  + 4096u*4u)               // float[1024]
#define OFF_WEFF   (OFF_BEFF + 1024u*4u)               // u16[1024*64]
#define OFF_WCAT   (OFF_WEFF + 65536u*2u)              // u16[32*1024]
#define OFF_S1     (OFF_WCAT + 32768u*2u)              // float[512*3]
#define OFF_S2     (OFF_S1   + 512u*3u*4u)             // float[2048*2]
#define OFF_S2V    (OFF_S2   + 2048u*2u*4u)            // float[1024]
#define OFF_S3     (OFF_S2V  + 2048u*4u)               // float[512*192]
#define OFF_S4     (OFF_S3   + 1024u*192u*4u)          // float[512*2]
#define OFF_H      (OFF_S4   + 2048u*2u*4u)            // float[32768*8]
#define OFF_W01    (OFF_H    + (size_t)B_SZ*8u*4u)     // float[NB_PAIR*2]
#define OFF_XAGG   (OFF_W01  + (size_t)NB_PAIR*2u*4u)  // u16[NB_PAIR*16]
#define OFF_XPROC  (OFF_XAGG + (size_t)NB_PAIR*16u*2u) // u16[NB_PAIR*16]
#define OFF_CAN    (OFF_XPROC+ (size_t)NB_PAIR*16u*2u) // canonical bf16 inputs

// canonical element offsets (u16 units, from OFF_CAN)
#define CAN_X      0u
#define CAN_WEMB   2097152u
#define CAN_WREAD  (CAN_WEMB + 65536u)
#define CAN_SCW1   (CAN_WREAD + 10240u)
#define CAN_SMALL  (CAN_SCW1 + 8192u)
#define CAN_TOTAL  (CAN_SMALL + 11008u)
#define OFF_BEX    (((OFF_CAN + (size_t)CAN_TOTAL*2u) + 63u) & ~(size_t)63u)
#define WS_NEEDED  (OFF_BEX + 48u*16u*2u)

__device__ __forceinline__ float bf2f(u16 u){
    unsigned v = ((unsigned)u) << 16;
    return __builtin_bit_cast(float, v);
}
__device__ __forceinline__ u16 f2bf(float f){
    unsigned u = __builtin_bit_cast(unsigned, f);
    u += 0x7FFFu + ((u >> 16) & 1u);           // RTN-even
    return (u16)(u >> 16);
}
__device__ __forceinline__ float sigm(float x){ return 1.f/(1.f + expf(-x)); }
__device__ __forceinline__ u16 conv_one(const void* src, int i, int isfp32){
    return isfp32 ? f2bf(((const float*)src)[i]) : ((const u16*)src)[i];
}
__device__ __forceinline__ void store_out(void* dout, int idx, float v, int isfp32){
    if (isfp32) ((float*)dout)[idx] = v;
    else        ((u16*)dout)[idx]   = f2bf(v);
}
// butterfly block reduction (256 threads), all threads uniform
__device__ __forceinline__ double blk_red(double v, double* sred, int tid){
    #pragma unroll
    for (int off = 32; off > 0; off >>= 1) v += __shfl_xor(v, off);
    if ((tid & 63) == 0) sred[tid >> 6] = v;
    __syncthreads();
    double r = sred[0] + sred[1] + sred[2] + sred[3];
    __syncthreads();
    return r;
}

// regulator: Linear(in_dim->16) -> LayerNorm -> *g+be -> tanh -> Linear(16->3) -> sigmoid
__device__ void run_regulator(const u16* w1, const u16* b1, const u16* g,
                              const u16* be, const u16* w2, const u16* b2,
                              const float* sig, int in_dim, float* out)
{
    float h[16];
    float mu = 0.f;
    for (int i = 0; i < 16; ++i){
        float a = bf2f(b1[i]);
        for (int j = 0; j < in_dim; ++j) a += sig[j]*bf2f(w1[i*in_dim + j]);
        h[i] = a; mu += a;
    }
    mu *= 0.0625f;
    float var = 0.f;
    for (int i = 0; i < 16; ++i){ float d = h[i]-mu; var += d*d; }
    var *= 0.0625f;
    float inv = 1.f / sqrtf(var + 1e-5f);
    for (int i = 0; i < 16; ++i){
        float hn = (h[i]-mu)*inv;
        h[i] = tanhf(hn*bf2f(g[i]) + bf2f(be[i]));
    }
    for (int c = 0; c < 3; ++c){
        float o = bf2f(b2[c]);
        for (int i = 0; i < 16; ++i) o += h[i]*bf2f(w2[c*16 + i]);
        out[c] = sigm(o);
    }
}

// KP: dtype probe. Even-indexed u16s of x: bf16 data -> sane exponents ~100%; fp32 -> ~20%.
__global__ __launch_bounds__(256) void kp_probe(const u16* xraw, float* scal)
{
    __shared__ int red[4];
    int tid = threadIdx.x, wave = tid>>6, lane = tid&63;
    int c = 0;
    #pragma unroll
    for (int j = 0; j < 4; ++j){
        u16 u = xraw[(tid*4 + j)*2];
        int e = (u >> 7) & 0xFF;
        if (u == 0 || (e >= 90 && e <= 140)) c++;
    }
    #pragma unroll
    for (int off = 32; off > 0; off >>= 1) c += __shfl_xor(c, off);
    if (lane == 0) red[wave] = c;
    __syncthreads();
    if (tid == 0){
        int tot = red[0]+red[1]+red[2]+red[3];
        scal[127] = (tot < 614) ? 1.0f : 0.0f;   // 1 => fp32 inputs
    }
}

// KCB: canonicalize the 4 big inputs to bf16
__global__ __launch_bounds__(256) void kc_big(const void* x, const void* wemb,
    const void* wread, const void* scw1, u16* can, const float* scal)
{
    int isfp32 = scal[127] != 0.f;
    int gid = blockIdx.x*256 + threadIdx.x, stride = gridDim.x*256;
    for (int i = gid; i < 2097152; i += stride) can[CAN_X + i]     = conv_one(x, i, isfp32);
    for (int i = gid; i < 65536;   i += stride) can[CAN_WEMB + i]  = conv_one(wemb, i, isfp32);
    for (int i = gid; i < 10240;   i += stride) can[CAN_WREAD + i] = conv_one(wread, i, isfp32);
    for (int i = gid; i < 8192;    i += stride) can[CAN_SCW1 + i]  = conv_one(scw1, i, isfp32);
}

// KCS: canonicalize 36 small inputs
struct SmallTab { const void* src[36]; int cnt[36]; int off[36]; };
__global__ __launch_bounds__(256) void kc_small(SmallTab t, u16* can, const float* scal)
{
    int isfp32 = scal[127] != 0.f;
    int gid = blockIdx.x*256 + threadIdx.x, stride = gridDim.x*256;
    for (int e = 0; e < 36; ++e){
        const void* s = t.src[e];
        u16* d = can + t.off[e];
        int n = t.cnt[e];
        for (int i = gid; i < n; i += stride) d[i] = conv_one(s, i, isfp32);
    }
}

// K0: Wcat[32][1024] = [W_read(10); sc_w1(8); zeros(14)]
__global__ __launch_bounds__(256) void k0_wcat(const u16* wread, const u16* scw1, u16* wcat)
{
    int idx = blockIdx.x*256 + threadIdx.x;
    int row = idx >> 10, k = idx & 1023;
    u16 v = 0;
    if (row < 10)      v = wread[row*1024 + k];
    else if (row < 18) v = scw1[(row-10)*1024 + k];
    wcat[idx] = v;
}

// K3c0: Bex rows 0-15 (V), row 32 (gv) + zero rows 35-47
__global__ __launch_bounds__(64) void k3c0(const u16* vslow, const u16* wfast,
                                           const u16* gatew, u16* bex)
{
    int r = threadIdx.x;
    if (r < 16) for (int k = 0; k < 16; ++k) bex[r*16+k] = vslow[r*16+k];
    else if (r == 32){
        for (int k = 0; k < 16; ++k){
            float a = 0.f;
            for (int i = 0; i < 16; ++i) a += bf2f(gatew[i])*bf2f(vslow[i*16+k]);
            bex[32*16+k] = f2bf(a);
        }
    }
    else if (r >= 35 && r < 48) for (int k = 0; k < 16; ++k) bex[r*16+k] = 0;
}

// K3c1 (after ctrl2 known): rows 16-31 = Bc = V + ctrl2*Wf; rows 33,34 = e0,e1
__global__ __launch_bounds__(64) void k3c1(const u16* vslow, const u16* wfast,
    const u16* wq, const u16* basis, const float* scal, u16* bex)
{
    int tid = threadIdx.x;
    float ctrl2 = scal[2];
    #pragma unroll
    for (int j = 0; j < 4; ++j){
        int idx = tid*4 + j;
        int d = idx >> 4, k = idx & 15;
        bex[(16+d)*16+k] = f2bf(bf2f(vslow[idx]) + ctrl2*bf2f(wfast[idx]));
    }
    if (tid < 32){
        int a = tid >> 4, k = tid & 15;
        float e = 0.f;
        for (int d = 0; d < 16; ++d){
            float bq = 0.f;
            for (int j = 0; j < 16; ++j) bq += bf2f(basis[a*16+j])*bf2f(wq[j*16+d]);
            e += bq*(bf2f(vslow[d*16+k]) + ctrl2*bf2f(wfast[d*16+k]));
        }
        bex[(33+a)*16+k] = f2bf(0.25f*e);
    }
}

// K1: MFMA x@W_embed^T (no store); stats sum|xe+b|, x sum/sumsq
__global__ __launch_bounds__(256) void k1_embed(const u16* x, const u16* wemb,
                                                const u16* bemb, float* s1)
{
    __shared__ float red[12];
    int tid = threadIdx.x, wave = tid>>6, lane = tid&63;
    int m = lane&15, quad = lane>>4;
    int row = blockIdx.x*64 + wave*16 + m;
    const u16* xr = x + row*64 + quad*8;
    short8 a0 = *(const short8*)xr;
    short8 a1 = *(const short8*)(xr + 32);
    float sx = 0.f, sxx = 0.f;
    #pragma unroll
    for (int j = 0; j < 8; ++j){
        float f0 = bf2f((u16)a0[j]); sx += f0; sxx += f0*f0;
        float f1 = bf2f((u16)a1[j]); sx += f1; sxx += f1*f1;
    }
    float sabs = 0.f;
    for (int t = 0; t < 64; ++t){
        int col = t*16 + m;
        const u16* wr = wemb + col*64 + quad*8;
        short8 b0 = *(const short8*)wr;
        short8 b1 = *(const short8*)(wr + 32);
        f32x4 acc = {0.f,0.f,0.f,0.f};
        acc = MFMA16(a0, b0, acc);
        acc = MFMA16(a1, b1, acc);
        float bias = bf2f(bemb[col]);
        sabs += fabsf(acc[0]+bias) + fabsf(acc[1]+bias)
              + fabsf(acc[2]+bias) + fabsf(acc[3]+bias);
    }
    #pragma unroll
    for (int off = 32; off > 0; off >>= 1){
        sx   += __shfl_xor(sx, off);
        sxx  += __shfl_xor(sxx, off);
        sabs += __shfl_xor(sabs, off);
    }
    if (lane == 0){ red[wave*3] = sx; red[wave*3+1] = sxx; red[wave*3+2] = sabs; }
    __syncthreads();
    if (tid == 0){
        for (int k = 0; k < 3; ++k)
            s1[blockIdx.x*3 + k] = red[k] + red[3+k] + red[6+k] + red[9+k];
    }
}

// K2 (1 block): stats -> regulator pr -> pl0; build normalized adj
__global__ __launch_bounds__(256) void k2_adj(const u16* adjw, const u16* adjm,
    const u16* w1, const u16* b1, const u16* g, const u16* be, const u16* w2, const u16* b2,
    const float* s1, float* scal, float* adj)
{
    __shared__ double sred[4];
    __shared__ float raw[4096];
    __shared__ float rowsum[64];
    __shared__ float pl0s;
    int tid = threadIdx.x;
    double s=0, ss=0, sa=0;
    for (int i = tid; i < 512; i += 256){
        s += (double)s1[i*3]; ss += (double)s1[i*3+1]; sa += (double)s1[i*3+2];
    }
    double nq = 0;
    for (int i = tid; i < 4096; i += 256){ float f = bf2f(adjw[i]); nq += (double)(f*f); }
    double S  = blk_red(s,  sred, tid);
    double SS = blk_red(ss, sred, tid);
    double SA = blk_red(sa, sred, tid);
    double NQ = blk_red(nq, sred, tid);
    if (tid == 0){
        double nx = 2097152.0;
        float sg[3];
        sg[0] = (float)((SS - S*S/nx)/(nx - 1.0));
        sg[1] = (float)(SA / 33554432.0);
        sg[2] = sqrtf((float)NQ);
        float o[3];
        run_regulator(w1,b1,g,be,w2,b2, sg, 3, o);
        scal[0] = o[0]; pl0s = o[0];
    }
    __syncthreads();
    float pl0 = pl0s;
    for (int i = tid; i < 4096; i += 256)
        raw[i] = sigm(bf2f(adjw[i])*pl0) * bf2f(adjm[i]);
    __syncthreads();
    if (tid < 64){
        float r = 0.f;
        for (int mc = 0; mc < 64; ++mc) r += raw[tid*64 + mc];
        rowsum[tid] = fmaxf(r, 1e-6f);
    }
    __syncthreads();
    for (int i = tid; i < 4096; i += 256) adj[i] = raw[i] / rowsum[i>>6];
}

// K2b: W_eff = adj-fold of W_embed
__global__ __launch_bounds__(256) void k2b_weff(const u16* wemb, const u16* bemb,
                                                const float* adj, u16* weff, float* beff)
{
    __shared__ float arow[64];
    int n = blockIdx.x, tid = threadIdx.x;
    if (tid < 64) arow[tid] = adj[n*64 + tid];
    __syncthreads();
    int k = tid & 63, dg = tid >> 6;
    for (int dd = 0; dd < 4; ++dd){
        int d = dg*4 + dd;
        float acc = 0.f;
        for (int mm = 0; mm < 64; ++mm)
            acc += arow[mm] * bf2f(wemb[(mm*16 + d)*64 + k]);
        weff[(n*16 + d)*64 + k] = f2bf(acc);
    }
    if (tid < 16){
        float acc = 0.f;
        for (int mm = 0; mm < 64; ++mm)
            acc += arow[mm] * bf2f(bemb[mm*16 + tid]);
        beff[n*16 + tid] = acc;
    }
}

// K3: MFMA x@W_eff^T + beff -> xagg + sum/sumsq stats
__global__ __launch_bounds__(256) void k3_agg(const u16* x, const u16* weff, const float* beff,
                                              u16* xagg, float* s2)
{
    __shared__ float red[8];
    int tid = threadIdx.x, wave = tid>>6, lane = tid&63;
    int m = lane&15, quad = lane>>4;
    int row0 = blockIdx.x*16;
    const u16* xr = x + (row0 + m)*64 + quad*8;
    short8 a0 = *(const short8*)xr;
    short8 a1 = *(const short8*)(xr + 32);
    float psum=0.f, pssq=0.f;
    for (int t = 0; t < 16; ++t){
        int col = wave*256 + t*16 + m;
        const u16* wr = weff + col*64 + quad*8;
        short8 b0 = *(const short8*)wr;
        short8 b1 = *(const short8*)(wr + 32);
        f32x4 acc = {0.f,0.f,0.f,0.f};
        acc = MFMA16(a0, b0, acc);
        acc = MFMA16(a1, b1, acc);
        float be = beff[col];
        #pragma unroll
        for (int r = 0; r < 4; ++r){
            float f = acc[r] + be;
            psum += f; pssq += f*f;
            xagg[(size_t)(row0 + quad*4 + r)*1024 + col] = f2bf(f);
        }
    }
    #pragma unroll
    for (int off = 32; off > 0; off >>= 1){
        psum += __shfl_xor(psum, off);
        pssq += __shfl_xor(pssq, off);
    }
    if (lane == 0){ red[wave] = psum; red[4+wave] = pssq; }
    __syncthreads();
    if (tid == 0){
        s2[blockIdx.x*2]   = red[0]+red[1]+red[2]+red[3];
        s2[blockIdx.x*2+1] = red[4]+red[5]+red[6]+red[7];
    }
}

// K3v: sum |x_agg @ V_slow^T| via MFMA (Bex rows 0-15). grid 1024 x 4 waves x 32 iters.
__global__ __launch_bounds__(256) void k3v_absv(const u16* xagg, const u16* bex, float* s2v)
{
    __shared__ float red[4];
    int tid = threadIdx.x, wave = tid>>6, lane = tid&63;
    int col = lane&15, quad = lane>>4;
    short8 z8 = {0,0,0,0,0,0,0,0};
    short8 b0 = z8;
    if (quad < 2) b0 = *(const short8*)(bex + col*16 + quad*8);
    float pabsv = 0.f;
    size_t wbase = ((size_t)blockIdx.x*4 + wave)*512;
    for (int it = 0; it < 32; ++it){
        size_t p0 = wbase + (size_t)it*16;
        short8 a = z8;
        if (quad < 2) a = *(const short8*)(xagg + (p0 + col)*16 + quad*8);
        f32x4 zc = {0.f,0.f,0.f,0.f};
        f32x4 c = MFMA16(a, b0, zc);
        pabsv += fabsf(c[0]) + fabsf(c[1]) + fabsf(c[2]) + fabsf(c[3]);
    }
    #pragma unroll
    for (int off = 32; off > 0; off >>= 1) pabsv += __shfl_xor(pabsv, off);
    if (lane == 0) red[wave] = pabsv;
    __syncthreads();
    if (tid == 0) s2v[blockIdx.x] = red[0]+red[1]+red[2]+red[3];
}

// K3b: ctrl regulator
__global__ __launch_bounds__(256) void k3b_ctrl(const u16* wslow,
    const u16* w1, const u16* b1, const u16* g, const u16* be, const u16* w2, const u16* b2,
    const float* s2, const float* s2v, float* scal)
{
    __shared__ double sred[4];
    int tid = threadIdx.x;
    double s=0, ss=0, sv=0;
    for (int i = tid; i < 2048; i += 256){
        s += (double)s2[i*2]; ss += (double)s2[i*2+1];
    }
    for (int i = tid; i < 1024; i += 256) sv += (double)s2v[i];
    float wf = bf2f(wslow[tid]);
    double nq = (double)(wf*wf);
    double S  = blk_red(s,  sred, tid);
    double SS = blk_red(ss, sred, tid);
    double SV = blk_red(sv, sred, tid);
    double NQ = blk_red(nq, sred, tid);
    if (tid == 0){
        double M = 33554432.0;
        float sg[3];
        sg[0] = (float)((SS - S*S/M)/(M - 1.0));
        sg[1] = (float)(SV / M);
        sg[2] = sqrtf((float)NQ);
        float o[3];
        run_regulator(w1,b1,g,be,w2,b2, sg, 3, o);
        scal[1] = o[0]; scal[2] = o[2];
    }
}

// K4: MFMA continuum+symbiotic, own-row epilogue.
// grid 512 x 4 waves; per wave 16 it2-groups of 64 pairs.
// Bex: rows 16-31 Bc=V+ctrl2*Wf; rows 32,33,34 gv,e0,e1 (zeros to 47).
__global__ __launch_bounds__(256) void k4_proc(const u16* xagg, const u16* bex,
    const u16* gateb, const float* scal, u16* xproc, float* wbuf, float* s3)
{
    __shared__ float scal3[4][192];
    __shared__ float part[4][192];
    int tid = threadIdx.x, wave = tid>>6, lane = tid&63;
    int col = lane & 15, quad = lane >> 4;
    short8 z8 = {0,0,0,0,0,0,0,0};
    short8 bc = z8, b2 = z8;
    if (quad < 2){
        bc = *(const short8*)(bex + (16+col)*16 + quad*8);
        b2 = *(const short8*)(bex + (32+col)*16 + quad*8);
    }
    float ctrl0 = scal[1];
    float gb = bf2f(gateb[0]);
    float psum[16], pssq[16];
    #pragma unroll
    for (int i = 0; i < 16; ++i){ psum[i] = 0.f; pssq[i] = 0.f; }
    float pent = 0.f;
    float* sc3 = scal3[wave];
    size_t wbase = ((size_t)blockIdx.x*4 + wave)*1024;
    for (int it2 = 0; it2 < 16; ++it2){
        size_t p0 = wbase + (size_t)it2*64;
        const u16* lbase = xagg + (p0 + col)*16 + quad*8;
        f32x4 cP[4], cS[4];
        #pragma unroll
        for (int g = 0; g < 4; ++g){
            short8 a = z8;
            if (quad < 2) a = *(const short8*)(lbase + g*256);
            f32x4 zc = {0.f,0.f,0.f,0.f};
            cP[g] = MFMA16(a, bc, zc);
            cS[g] = MFMA16(a, b2, zc);
        }
        // scatter per-row scalars (gd,e0,e1 live in cols 0..2) to LDS
        if (col < 3){
            #pragma unroll
            for (int g = 0; g < 4; ++g)
                #pragma unroll
                for (int r = 0; r < 4; ++r)
                    sc3[(g*16 + quad*4 + r)*3 + col] = cS[g][r];
        }
        // own-row epilogue: lane owns row=lane (in-order DS pipe within wave)
        float gd  = sc3[lane*3 + 0];
        float e0d = sc3[lane*3 + 1];
        float e1d = sc3[lane*3 + 2];
        float gate_own = ctrl0 / (1.f + __expf(-(gd + gb)));
        float l0 = gate_own*e0d, l1 = gate_own*e1d;
        float w1v = 1.f/(1.f + __expf(l0 - l1));
        float w0v = 1.f - w1v;
        pent += -(w0v*__logf(w0v + 1e-8f) + w1v*__logf(w1v + 1e-8f));
        float2 wv; wv.x = w0v; wv.y = w1v;
        *(float2*)(wbuf + (p0 + lane)*2) = wv;
        // xp = gate * (x @ Bc^T); gate broadcast from row-owner lane
        u16* sbase = xproc + (p0 + (size_t)quad*4)*16 + col;
        #pragma unroll
        for (int g = 0; g < 4; ++g){
            #pragma unroll
            for (int r = 0; r < 4; ++r){
                float gate = __shfl(gate_own, g*16 + ((lane & 48) >> 2) + r);
                float xp = gate * cP[g][r];
                psum[g*4+r] += xp; pssq[g*4+r] += xp*xp;
                sbase[g*256 + r*16] = f2bf(xp);
            }
        }
    }
    #pragma unroll
    for (int i = 0; i < 16; ++i){
        float a = psum[i], b = pssq[i];
        #pragma unroll
        for (int off = 1; off < 16; off <<= 1){
            a += __shfl_xor(a, off);
            b += __shfl_xor(b, off);
        }
        if (col == 0){
            int n = (i >> 2)*16 + quad*4 + (i & 3);
            part[wave][n]      = a;
            part[wave][64 + n] = b;
        }
    }
    part[wave][128 + lane] = pent;
    __syncthreads();
    if (tid < 192)
        s3[(size_t)blockIdx.x*192 + tid] =
            part[0][tid] + part[1][tid] + part[2][tid] + part[3][tid];
}

// K5: per-node regulator -> infl[64]; entropy(node63), ortho. 1024 thr, 4-way sliced reduce.
__global__ __launch_bounds__(1024) void k5_infl(const u16* basis,
    const u16* w1, const u16* b1, const u16* g, const u16* be, const u16* w2, const u16* b2,
    const float* s3, float* scal, void* dout)
{
    __shared__ double nstp[4*192];
    __shared__ double nst[192];
    int tid = threadIdx.x;
    int c = tid & 255, sl = tid >> 8;
    if (c < 192){
        double a = 0;
        for (int i = sl; i < 512; i += 4) a += (double)s3[(size_t)i*192 + c];
        nstp[sl*192 + c] = a;
    }
    __syncthreads();
    if (tid < 192) nst[tid] = nstp[tid] + nstp[192+tid] + nstp[384+tid] + nstp[576+tid];
    __syncthreads();
    int isfp32 = scal[127] != 0.f;
    if (tid < 64){
        int n = tid;
        double sum = nst[n], ssq = nst[64+n], ent = nst[128+n];
        double Mn = 524288.0;
        float varn = (float)((ssq - sum*sum/Mn)/(Mn - 1.0));
        float entm = (float)(ent / 32768.0);
        float b0[16], b1v[16];
        for (int d = 0; d < 16; ++d){ b0[d] = bf2f(basis[d]); b1v[d] = bf2f(basis[16+d]); }
        float g00=0.f, g01=0.f, g11=0.f;
        for (int d = 0; d < 16; ++d){ g00 += b0[d]*b0[d]; g01 += b0[d]*b1v[d]; g11 += b1v[d]*b1v[d]; }
        float ortho = sqrtf((g00-1.f)*(g00-1.f) + 2.f*g01*g01 + (g11-1.f)*(g11-1.f));
        float sg[3] = {varn, entm, ortho};
        float o[3];
        run_regulator(w1,b1,g,be,w2,b2, sg, 3, o);
        scal[4+n] = o[0];
        if (n == 63){ scal[68] = entm;  store_out(dout, OUT_ENT,   entm,  isfp32); }
        if (n == 0) { scal[69] = ortho; store_out(dout, OUT_ORTHO, ortho, isfp32); }
    }
}

// K6: blend-on-load + MFMA GEMM [B x 1024] @ Wcat^T -> logits, relu h, x_flat stats.
__global__ __launch_bounds__(256) void k6_read(const u16* xproc, const float* wbuf, const u16* wcat,
    const u16* basis, const u16* bread, const float* scal,
    void* dout, float* hbuf, float* s4)
{
    __shared__ float infl_s[64], b0s[16], b1s[16], brd[16];
    __shared__ float red[8];
    int tid = threadIdx.x;
    int isfp32 = scal[127] != 0.f;
    if (tid < 64) infl_s[tid] = scal[4+tid];
    if (tid < 16){
        b0s[tid] = bf2f(basis[tid]);
        b1s[tid] = bf2f(basis[16+tid]);
        brd[tid] = (tid < 10) ? bf2f(bread[tid]) : 0.f;
    }
    __syncthreads();
    int wave = tid>>6, lane = tid&63;
    int m = lane&15, quad = lane>>4;
    int row = blockIdx.x*64 + wave*16 + m;
    const u16* xrow = xproc + (size_t)row*1024;
    f32x4 acc0 = {0.f,0.f,0.f,0.f}, acc1 = {0.f,0.f,0.f,0.f};
    float psum = 0.f, pssq = 0.f;
    for (int kc = 0; kc < 1024; kc += 32){
        int kb = kc + quad*8;
        int n  = kb >> 4;
        int d0 = kb & 15;
        short8 xp = *(const short8*)(xrow + kb);
        float2 wv = *(const float2*)(wbuf + ((size_t)row*64 + n)*2);
        float fi = infl_s[n], om = 1.f - fi;
        short8 af;
        #pragma unroll
        for (int j = 0; j < 8; ++j){
            int d = d0 + j;
            float xf = om*bf2f((u16)xp[j]) + fi*(wv.x*b0s[d] + wv.y*b1s[d]);
            psum += xf; pssq += xf*xf;
            af[j] = (short)f2bf(xf);
        }
        short8 bb0 = *(const short8*)(wcat + m*1024 + kb);
        short8 bb1 = *(const short8*)(wcat + (16+m)*1024 + kb);
        acc0 = MFMA16(af, bb0, acc0);
        acc1 = MFMA16(af, bb1, acc1);
    }
    int rowbase = blockIdx.x*64 + wave*16 + quad*4;
    #pragma unroll
    for (int r = 0; r < 4; ++r){
        int rowg = rowbase + r;
        if (m < 10) store_out(dout, rowg*10 + m, acc0[r] + brd[m], isfp32);
        else        hbuf[rowg*8 + (m-10)] = fmaxf(acc0[r], 0.f);
        if (m < 2)  hbuf[rowg*8 + 6 + m]  = fmaxf(acc1[r], 0.f);
    }
    #pragma unroll
    for (int off = 32; off > 0; off >>= 1){
        psum += __shfl_xor(psum, off);
        pssq += __shfl_xor(pssq, off);
    }
    if (lane == 0){ red[wave] = psum; red[4+wave] = pssq; }
    __syncthreads();
    if (tid == 0){
        s4[blockIdx.x*2]   = red[0]+red[1]+red[2]+red[3];
        s4[blockIdx.x*2+1] = red[4]+red[5]+red[6]+red[7];
    }
}

// K7: gain regulator
__global__ __launch_bounds__(256) void k7_gain(
    const u16* w1, const u16* b1, const u16* g, const u16* be, const u16* w2, const u16* b2,
    const float* s4, float* scal)
{
    __shared__ double sred[4];
    int tid = threadIdx.x;
    double s=0, ss=0;
    for (int i = tid; i < 512; i += 256){ s += (double)s4[i*2]; ss += (double)s4[i*2+1]; }
    double S  = blk_red(s,  sred, tid);
    double SS = blk_red(ss, sred, tid);
    if (tid == 0){
        double M = 33554432.0;
        float sg[2];
        sg[0] = (float)((SS - S*S/M)/(M - 1.0));
        sg[1] = scal[68];
        float o[3];
        run_regulator(w1,b1,g,be,w2,b2, sg, 2, o);
        scal[3] = o[0];
    }
}

// K8: proj = (h @ sc_w2^T) * gain
__global__ __launch_bounds__(256) void k8_proj(const float* hbuf, const u16* scw2,
                                               const float* scal, void* dout)
{
    __shared__ float w2s[32];
    int tid = threadIdx.x;
    int isfp32 = scal[127] != 0.f;
    if (tid < 32) w2s[tid] = bf2f(scw2[tid]);
    __syncthreads();
    int b = blockIdx.x*256 + tid;
    float gain = scal[3];
    const float* h = hbuf + (size_t)b*8;
    float hv[8];
    #pragma unroll
    for (int k = 0; k < 8; ++k) hv[k] = h[k];
    #pragma unroll
    for (int i = 0; i < 4; ++i){
        float o = 0.f;
        #pragma unroll
        for (int k = 0; k < 8; ++k) o += hv[k]*w2s[i*8+k];
        store_out(dout, OUT_PROJ + b*4 + i, o*gain, isfp32);
    }
}

extern "C" void kernel_launch(void* const* d_in, const int* in_sizes, int n_in,
                              void* d_out, int out_size, void* d_ws, size_t ws_size,
                              hipStream_t stream)
{
    if (ws_size < WS_NEEDED) return;

    char* ws = (char*)d_ws;
    float* scal  = (float*)(ws + OFF_SCAL);
    float* adj   = (float*)(ws + OFF_ADJ);
    float* beff  = (float*)(ws + OFF_BEFF);
    u16*   weff  = (u16*)  (ws + OFF_WEFF);
    u16*   wcat  = (u16*)  (ws + OFF_WCAT);
    float* s1    = (float*)(ws + OFF_S1);
    float* s2    = (float*)(ws + OFF_S2);
    float* s2v   = (float*)(ws + OFF_S2V);
    float* s3    = (float*)(ws + OFF_S3);
    float* s4    = (float*)(ws + OFF_S4);
    float* hbuf  = (float*)(ws + OFF_H);
    float* wbuf  = (float*)(ws + OFF_W01);
    u16*   xagg  = (u16*)  (ws + OFF_XAGG);
    u16*   xproc = (u16*)  (ws + OFF_XPROC);
    u16*   can   = (u16*)  (ws + OFF_CAN);
    u16*   bex   = (u16*)  (ws + OFF_BEX);

    static const int sidx[36] = {2,3,4,5,6,7,8,9,10,11,13,15,
        16,17,18,19,20,21, 22,23,24,25,26,27, 28,29,30,31,32,33, 34,35,36,37,38,39};
    static const int scnt[36] = {1024,4096,4096,256,256,16,1,256,32,256,32,10,
        48,16,16,16,48,3, 48,16,16,16,48,3, 48,16,16,16,48,3, 32,16,16,16,48,3};
    SmallTab t;
    const u16* canp[40];
    {
        int off = (int)CAN_SMALL;
        for (int j = 0; j < 36; ++j){
            t.src[j] = d_in[sidx[j]];
            t.cnt[j] = scnt[j];
            t.off[j] = off;
            canp[sidx[j]] = can + off;
            off += (scnt[j] + 7) & ~7;
        }
    }
    canp[0]  = can + CAN_X;
    canp[1]  = can + CAN_WEMB;
    canp[12] = can + CAN_SCW1;
    canp[14] = can + CAN_WREAD;

    const u16* pr_[6]; const u16* cr_[6]; const u16* sr_[6]; const u16* sc_[6];
    for (int i = 0; i < 6; ++i){
        pr_[i] = canp[16+i]; cr_[i] = canp[22+i];
        sr_[i] = canp[28+i]; sc_[i] = canp[34+i];
    }

    kp_probe<<<1,   256, 0, stream>>>((const u16*)d_in[0], scal);
    kc_big  <<<1024,256, 0, stream>>>(d_in[0], d_in[1], d_in[14], d_in[12], can, scal);
    kc_small<<<16,  256, 0, stream>>>(t, can, scal);
    k0_wcat <<<128, 256, 0, stream>>>(canp[14], canp[12], wcat);
    k3c0    <<<1,   64,  0, stream>>>(canp[5], canp[9], canp[7], bex);
    k1_embed<<<512, 256, 0, stream>>>(canp[0], canp[1], canp[2], s1);
    k2_adj  <<<1,   256, 0, stream>>>(canp[3], canp[4],
                 pr_[0],pr_[1],pr_[2],pr_[3],pr_[4],pr_[5], s1, scal, adj);
    k2b_weff<<<64,  256, 0, stream>>>(canp[1], canp[2], adj, weff, beff);
    k3_agg  <<<2048,256, 0, stream>>>(canp[0], weff, beff, xagg, s2);
    k3v_absv<<<1024,256, 0, stream>>>(xagg, bex, s2v);
    k3b_ctrl<<<1,   256, 0, stream>>>(canp[6],
                 cr_[0],cr_[1],cr_[2],cr_[3],cr_[4],cr_[5], s2, s2v, scal);
    k3c1    <<<1,   64,  0, stream>>>(canp[5], canp[9], canp[11], canp[10], scal, bex);
    k4_proc <<<512, 256, 0, stream>>>(xagg, bex, canp[8], scal, xproc, wbuf, s3);
    k5_infl <<<1,  1024, 0, stream>>>(canp[10],
                 sr_[0],sr_[1],sr_[2],sr_[3],sr_[4],sr_[5], s3, scal, d_out);
    k6_read <<<512, 256, 0, stream>>>(xproc, wbuf, wcat, canp[10], canp[15], scal,
                 d_out, hbuf, s4);
    k7_gain <<<1,   256, 0, stream>>>(
                 sc_[0],sc_[1],sc_[2],sc_[3],sc_[4],sc_[5], s4, scal);
    k8_proj <<<128, 256, 0, stream>>>(hbuf, canp[13], scal, d_out);
}

// Round 6
// 414.337 us; speedup vs baseline: 1.5633x; 1.0841x over previous
//
#include <hip/hip_runtime.h>

typedef unsigned short u16;
typedef __attribute__((ext_vector_type(8))) short short8;
typedef __attribute__((ext_vector_type(4))) float f32x4;

#define MFMA16(a,b,c) __builtin_amdgcn_mfma_f32_16x16x32_bf16(a,b,c,0,0,0)

// ---- problem constants ----
#define B_SZ   32768
#define NNODE  64
#define NB_PAIR (B_SZ*NNODE)           // 2097152
#define OUT_PROJ   327680
#define OUT_ENT    458752
#define OUT_ORTHO  458753

// ---- workspace byte offsets ----
#define OFF_SCAL   ((size_t)0)                         // float[128]; [127] = isfp32 flag
#define OFF_ADJ    ((size_t)512)                       // u16[4096] adjb (bf16 normalized adj)
#define OFF_BEFF   (OFF_ADJ  + 4096u*4u)               // float[1024]
#define OFF_WEFF   (OFF_BEFF + 1024u*4u)               // u16[1024*64]
#define OFF_WCAT   (OFF_WEFF + 65536u*2u)              // u16[32*1024]
#define OFF_S1     (OFF_WCAT + 32768u*2u)              // float[512*3]
#define OFF_S2     (OFF_S1   + 512u*3u*4u)             // float[2048*3]
#define OFF_S3     (OFF_S2   + 2048u*3u*4u)            // float[512*192]
#define OFF_S4     (OFF_S3   + 1024u*192u*4u)          // float[512*2]
#define OFF_H      (OFF_S4   + 2048u*2u*4u)            // float[32768*8]
#define OFF_W01    (OFF_H    + (size_t)B_SZ*8u*4u)     // float[NB_PAIR*2]
#define OFF_XAGG   (OFF_W01  + (size_t)NB_PAIR*2u*4u)  // u16[NB_PAIR*16]
#define OFF_XPROC  (OFF_XAGG + (size_t)NB_PAIR*16u*2u) // u16[NB_PAIR*16]
#define OFF_CAN    (OFF_XPROC+ (size_t)NB_PAIR*16u*2u) // canonical bf16 inputs

// canonical element offsets (u16 units, from OFF_CAN)
#define CAN_X      0u
#define CAN_WEMB   2097152u
#define CAN_WREAD  (CAN_WEMB + 65536u)
#define CAN_SCW1   (CAN_WREAD + 10240u)
#define CAN_SMALL  (CAN_SCW1 + 8192u)
#define CAN_TOTAL  (CAN_SMALL + 11008u)
#define OFF_BEX    (((OFF_CAN + (size_t)CAN_TOTAL*2u) + 63u) & ~(size_t)63u)
#define OFF_WET    (OFF_BEX + 48u*16u*2u)              // u16[1024*64] wembT
#define OFF_VW     (OFF_WET + 65536u*2u)               // u16[1024*64] Vw
#define OFF_VB     (OFF_VW  + 65536u*2u)               // float[1024] vbias
#define WS_NEEDED  (OFF_VB  + 1024u*4u)

__device__ __forceinline__ float bf2f(u16 u){
    unsigned v = ((unsigned)u) << 16;
    return __builtin_bit_cast(float, v);
}
__device__ __forceinline__ u16 f2bf(float f){
    unsigned u = __builtin_bit_cast(unsigned, f);
    u += 0x7FFFu + ((u >> 16) & 1u);           // RTN-even
    return (u16)(u >> 16);
}
__device__ __forceinline__ float sigm(float x){ return 1.f/(1.f + expf(-x)); }
__device__ __forceinline__ u16 conv_one(const void* src, int i, int isfp32){
    return isfp32 ? f2bf(((const float*)src)[i]) : ((const u16*)src)[i];
}
__device__ __forceinline__ void store_out(void* dout, int idx, float v, int isfp32){
    if (isfp32) ((float*)dout)[idx] = v;
    else        ((u16*)dout)[idx]   = f2bf(v);
}
// butterfly block reduction (256 threads), all threads uniform
__device__ __forceinline__ double blk_red(double v, double* sred, int tid){
    #pragma unroll
    for (int off = 32; off > 0; off >>= 1) v += __shfl_xor(v, off);
    if ((tid & 63) == 0) sred[tid >> 6] = v;
    __syncthreads();
    double r = sred[0] + sred[1] + sred[2] + sred[3];
    __syncthreads();
    return r;
}

// regulator: Linear(in_dim->16) -> LayerNorm -> *g+be -> tanh -> Linear(16->3) -> sigmoid
__device__ void run_regulator(const u16* w1, const u16* b1, const u16* g,
                              const u16* be, const u16* w2, const u16* b2,
                              const float* sig, int in_dim, float* out)
{
    float h[16];
    float mu = 0.f;
    for (int i = 0; i < 16; ++i){
        float a = bf2f(b1[i]);
        for (int j = 0; j < in_dim; ++j) a += sig[j]*bf2f(w1[i*in_dim + j]);
        h[i] = a; mu += a;
    }
    mu *= 0.0625f;
    float var = 0.f;
    for (int i = 0; i < 16; ++i){ float d = h[i]-mu; var += d*d; }
    var *= 0.0625f;
    float inv = 1.f / sqrtf(var + 1e-5f);
    for (int i = 0; i < 16; ++i){
        float hn = (h[i]-mu)*inv;
        h[i] = tanhf(hn*bf2f(g[i]) + bf2f(be[i]));
    }
    for (int c = 0; c < 3; ++c){
        float o = bf2f(b2[c]);
        for (int i = 0; i < 16; ++i) o += h[i]*bf2f(w2[c*16 + i]);
        out[c] = sigm(o);
    }
}

// KP: dtype probe. Even-indexed u16s of x: bf16 data -> sane exponents ~100%; fp32 -> ~20%.
__global__ __launch_bounds__(256) void kp_probe(const u16* xraw, float* scal)
{
    __shared__ int red[4];
    int tid = threadIdx.x, wave = tid>>6, lane = tid&63;
    int c = 0;
    #pragma unroll
    for (int j = 0; j < 4; ++j){
        u16 u = xraw[(tid*4 + j)*2];
        int e = (u >> 7) & 0xFF;
        if (u == 0 || (e >= 90 && e <= 140)) c++;
    }
    #pragma unroll
    for (int off = 32; off > 0; off >>= 1) c += __shfl_xor(c, off);
    if (lane == 0) red[wave] = c;
    __syncthreads();
    if (tid == 0){
        int tot = red[0]+red[1]+red[2]+red[3];
        scal[127] = (tot < 614) ? 1.0f : 0.0f;   // 1 => fp32 inputs
    }
}

// KCB: canonicalize the 4 big inputs to bf16
__global__ __launch_bounds__(256) void kc_big(const void* x, const void* wemb,
    const void* wread, const void* scw1, u16* can, const float* scal)
{
    int isfp32 = scal[127] != 0.f;
    int gid = blockIdx.x*256 + threadIdx.x, stride = gridDim.x*256;
    for (int i = gid; i < 2097152; i += stride) can[CAN_X + i]     = conv_one(x, i, isfp32);
    for (int i = gid; i < 65536;   i += stride) can[CAN_WEMB + i]  = conv_one(wemb, i, isfp32);
    for (int i = gid; i < 10240;   i += stride) can[CAN_WREAD + i] = conv_one(wread, i, isfp32);
    for (int i = gid; i < 8192;    i += stride) can[CAN_SCW1 + i]  = conv_one(scw1, i, isfp32);
}

// KCS: canonicalize 36 small inputs
struct SmallTab { const void* src[36]; int cnt[36]; int off[36]; };
__global__ __launch_bounds__(256) void kc_small(SmallTab t, u16* can, const float* scal)
{
    int isfp32 = scal[127] != 0.f;
    int gid = blockIdx.x*256 + threadIdx.x, stride = gridDim.x*256;
    for (int e = 0; e < 36; ++e){
        const void* s = t.src[e];
        u16* d = can + t.off[e];
        int n = t.cnt[e];
        for (int i = gid; i < n; i += stride) d[i] = conv_one(s, i, isfp32);
    }
}

// K0: blocks 0-127 Wcat; 128-383 wembT transpose; 384 bex static rows (gv row32, zero 35-47)
__global__ __launch_bounds__(256) void k0_wcat(const u16* wread, const u16* scw1,
    const u16* wemb, const u16* vslow, const u16* gatew, u16* wcat, u16* wembT, u16* bex)
{
    int b = blockIdx.x, tid = threadIdx.x;
    if (b < 128){
        int idx = b*256 + tid;
        int row = idx >> 10, k = idx & 1023;
        u16 v = 0;
        if (row < 10)      v = wread[row*1024 + k];
        else if (row < 18) v = scw1[(row-10)*1024 + k];
        wcat[idx] = v;
    } else if (b < 384){
        int idx = (b-128)*256 + tid;     // 65536
        int m = idx >> 10, jj = idx & 1023;
        wembT[jj*64 + m] = wemb[m*1024 + jj];    // coalesced reads
    } else {
        if (tid < 16){
            float a = 0.f;
            for (int i = 0; i < 16; ++i) a += bf2f(gatew[i])*bf2f(vslow[i*16+tid]);
            bex[32*16+tid] = f2bf(a);
        } else if (tid >= 32 && tid < 240){
            bex[35*16 + (tid-32)] = 0;           // zero rows 35-47
        }
    }
}

// K1: MFMA x@W_embed^T (no store); stats sum|xe+b|, x sum/sumsq
__global__ __launch_bounds__(256) void k1_embed(const u16* x, const u16* wemb,
                                                const u16* bemb, float* s1)
{
    __shared__ float red[12];
    int tid = threadIdx.x, wave = tid>>6, lane = tid&63;
    int m = lane&15, quad = lane>>4;
    int row = blockIdx.x*64 + wave*16 + m;
    const u16* xr = x + row*64 + quad*8;
    short8 a0 = *(const short8*)xr;
    short8 a1 = *(const short8*)(xr + 32);
    float sx = 0.f, sxx = 0.f;
    #pragma unroll
    for (int j = 0; j < 8; ++j){
        float f0 = bf2f((u16)a0[j]); sx += f0; sxx += f0*f0;
        float f1 = bf2f((u16)a1[j]); sx += f1; sxx += f1*f1;
    }
    float sabs = 0.f;
    for (int t = 0; t < 64; ++t){
        int col = t*16 + m;
        const u16* wr = wemb + col*64 + quad*8;
        short8 b0 = *(const short8*)wr;
        short8 b1 = *(const short8*)(wr + 32);
        f32x4 acc = {0.f,0.f,0.f,0.f};
        acc = MFMA16(a0, b0, acc);
        acc = MFMA16(a1, b1, acc);
        float bias = bf2f(bemb[col]);
        sabs += fabsf(acc[0]+bias) + fabsf(acc[1]+bias)
              + fabsf(acc[2]+bias) + fabsf(acc[3]+bias);
    }
    #pragma unroll
    for (int off = 32; off > 0; off >>= 1){
        sx   += __shfl_xor(sx, off);
        sxx  += __shfl_xor(sxx, off);
        sabs += __shfl_xor(sabs, off);
    }
    if (lane == 0){ red[wave*3] = sx; red[wave*3+1] = sxx; red[wave*3+2] = sabs; }
    __syncthreads();
    if (tid == 0){
        for (int k = 0; k < 3; ++k)
            s1[blockIdx.x*3 + k] = red[k] + red[3+k] + red[6+k] + red[9+k];
    }
}

// K2 (1 block): stats -> regulator pr -> pl0; build normalized adjb (bf16) + beff
__global__ __launch_bounds__(256) void k2_adj(const u16* adjw, const u16* adjm, const u16* bemb,
    const u16* w1, const u16* b1, const u16* g, const u16* be, const u16* w2, const u16* b2,
    const float* s1, float* scal, u16* adjb, float* beff)
{
    __shared__ double sred[4];
    __shared__ float raw[4096];
    __shared__ float rowsum[64];
    __shared__ float bembs[1024];
    __shared__ float pl0s;
    int tid = threadIdx.x;
    for (int i = tid; i < 1024; i += 256) bembs[i] = bf2f(bemb[i]);
    double s=0, ss=0, sa=0;
    for (int i = tid; i < 512; i += 256){
        s += (double)s1[i*3]; ss += (double)s1[i*3+1]; sa += (double)s1[i*3+2];
    }
    double nq = 0;
    for (int i = tid; i < 4096; i += 256){ float f = bf2f(adjw[i]); nq += (double)(f*f); }
    double S  = blk_red(s,  sred, tid);
    double SS = blk_red(ss, sred, tid);
    double SA = blk_red(sa, sred, tid);
    double NQ = blk_red(nq, sred, tid);
    if (tid == 0){
        double nx = 2097152.0;
        float sg[3];
        sg[0] = (float)((SS - S*S/nx)/(nx - 1.0));
        sg[1] = (float)(SA / 33554432.0);
        sg[2] = sqrtf((float)NQ);
        float o[3];
        run_regulator(w1,b1,g,be,w2,b2, sg, 3, o);
        scal[0] = o[0]; pl0s = o[0];
    }
    __syncthreads();
    float pl0 = pl0s;
    for (int i = tid; i < 4096; i += 256)
        raw[i] = sigm(bf2f(adjw[i])*pl0) * bf2f(adjm[i]);
    __syncthreads();
    if (tid < 64){
        float r = 0.f;
        for (int mc = 0; mc < 64; ++mc) r += raw[tid*64 + mc];
        rowsum[tid] = fmaxf(r, 1e-6f);
    }
    __syncthreads();
    for (int i = tid; i < 4096; i += 256) adjb[i] = f2bf(raw[i] / rowsum[i>>6]);
    for (int o = tid; o < 1024; o += 256){
        int n = o >> 4, d = o & 15;
        float a = 0.f;
        for (int m = 0; m < 64; ++m) a += raw[n*64+m]*bembs[m*16+d];
        beff[o] = a / rowsum[n];
    }
}

// K2b (MFMA): Weff = adjb @ Wr. 64 blocks (col-tiles) x 4 waves (row-tiles).
__global__ __launch_bounds__(256) void k2b_mfma(const u16* adjb, const u16* wembT, u16* weff)
{
    int tid = threadIdx.x, wave = tid>>6, lane = tid&63;
    int m = lane&15, quad = lane>>4;
    const u16* ar = adjb + (wave*16 + m)*64 + quad*8;
    short8 a0 = *(const short8*)ar;
    short8 a1 = *(const short8*)(ar + 32);
    int col = blockIdx.x*16 + m;
    const u16* br = wembT + col*64 + quad*8;
    short8 b0 = *(const short8*)br;
    short8 b1 = *(const short8*)(br + 32);
    f32x4 acc = {0.f,0.f,0.f,0.f};
    acc = MFMA16(a0, b0, acc);
    acc = MFMA16(a1, b1, acc);
    #pragma unroll
    for (int r = 0; r < 4; ++r)
        weff[(size_t)(wave*16 + quad*4 + r)*1024 + blockIdx.x*16 + m] = f2bf(acc[r]);
}

// KVW: Vw[n*16+i][kf] = sum_d V[i][d]*Weff[(n*16+d)][kf]; vbias[n*16+i] = sum_d V[i][d]*beff[n*16+d]
__global__ __launch_bounds__(256) void kvw(const u16* vslow, const u16* weff, const float* beff,
                                           u16* vw, float* vbias)
{
    __shared__ float Vs[256];
    int tid = threadIdx.x, b = blockIdx.x;
    Vs[tid] = bf2f(vslow[tid]);
    __syncthreads();
    if (b < 256){
        int idx = b*256 + tid;       // 65536
        int j = idx >> 6, kf = idx & 63;
        int n = j >> 4, i = j & 15;
        float a = 0.f;
        #pragma unroll
        for (int d = 0; d < 16; ++d) a += Vs[i*16+d]*bf2f(weff[(size_t)(n*16+d)*64 + kf]);
        vw[(size_t)j*64 + kf] = f2bf(a);
    } else {
        int o = (b-256)*256 + tid;   // 1024
        int n = o >> 4, i = o & 15;
        float a = 0.f;
        #pragma unroll
        for (int d = 0; d < 16; ++d) a += Vs[i*16+d]*beff[n*16+d];
        vbias[o] = a;
    }
}

// K3: MFMA x@W_eff^T + beff -> xagg + sum/sumsq; fused sum|v| via x@Vw^T + vbias.
__global__ __launch_bounds__(256) void k3_agg(const u16* x, const u16* weff, const float* beff,
                                              const u16* vw, const float* vbias,
                                              u16* xagg, float* s2)
{
    __shared__ float red[12];
    int tid = threadIdx.x, wave = tid>>6, lane = tid&63;
    int m = lane&15, quad = lane>>4;
    int row0 = blockIdx.x*16;
    const u16* xr = x + (row0 + m)*64 + quad*8;
    short8 a0 = *(const short8*)xr;
    short8 a1 = *(const short8*)(xr + 32);
    float psum=0.f, pssq=0.f, pabsv=0.f;
    for (int t = 0; t < 16; ++t){
        int col = wave*256 + t*16 + m;
        const u16* wr = weff + (size_t)col*64 + quad*8;
        short8 b0 = *(const short8*)wr;
        short8 b1 = *(const short8*)(wr + 32);
        const u16* vr = vw + (size_t)col*64 + quad*8;
        short8 v0 = *(const short8*)vr;
        short8 v1 = *(const short8*)(vr + 32);
        f32x4 zc = {0.f,0.f,0.f,0.f};
        f32x4 acc = MFMA16(a0, b0, zc);
        acc = MFMA16(a1, b1, acc);
        f32x4 av = MFMA16(a0, v0, zc);
        av = MFMA16(a1, v1, av);
        float be = beff[col];
        float vb = vbias[col];
        #pragma unroll
        for (int r = 0; r < 4; ++r){
            float f = acc[r] + be;
            psum += f; pssq += f*f;
            pabsv += fabsf(av[r] + vb);
            xagg[(size_t)(row0 + quad*4 + r)*1024 + col] = f2bf(f);
        }
    }
    #pragma unroll
    for (int off = 32; off > 0; off >>= 1){
        psum  += __shfl_xor(psum, off);
        pssq  += __shfl_xor(pssq, off);
        pabsv += __shfl_xor(pabsv, off);
    }
    if (lane == 0){ red[wave*3] = psum; red[wave*3+1] = pssq; red[wave*3+2] = pabsv; }
    __syncthreads();
    if (tid == 0){
        for (int k = 0; k < 3; ++k)
            s2[blockIdx.x*3 + k] = red[k] + red[3+k] + red[6+k] + red[9+k];
    }
}

// K3b: ctrl regulator + build dynamic bex rows (16-31 Bc = V+ctrl2*Wf; 33,34 = e0,e1)
__global__ __launch_bounds__(256) void k3b_ctrl(const u16* wslow,
    const u16* vslow, const u16* wfast, const u16* wq, const u16* basis,
    const u16* w1, const u16* b1, const u16* g, const u16* be, const u16* w2, const u16* b2,
    const float* s2, float* scal, u16* bex)
{
    __shared__ double sred[4];
    __shared__ float ctrl2s;
    int tid = threadIdx.x;
    double s=0, ss=0, sv=0;
    for (int i = tid; i < 2048; i += 256){
        s += (double)s2[i*3]; ss += (double)s2[i*3+1]; sv += (double)s2[i*3+2];
    }
    float wf = bf2f(wslow[tid]);
    double nq = (double)(wf*wf);
    double S  = blk_red(s,  sred, tid);
    double SS = blk_red(ss, sred, tid);
    double SV = blk_red(sv, sred, tid);
    double NQ = blk_red(nq, sred, tid);
    if (tid == 0){
        double M = 33554432.0;
        float sg[3];
        sg[0] = (float)((SS - S*S/M)/(M - 1.0));
        sg[1] = (float)(SV / M);
        sg[2] = sqrtf((float)NQ);
        float o[3];
        run_regulator(w1,b1,g,be,w2,b2, sg, 3, o);
        scal[1] = o[0]; scal[2] = o[2];
        ctrl2s = o[2];
    }
    __syncthreads();
    float ctrl2 = ctrl2s;
    if (tid < 64){
        #pragma unroll
        for (int j = 0; j < 4; ++j){
            int idx = tid*4 + j;
            int d = idx >> 4, k = idx & 15;
            bex[(16+d)*16+k] = f2bf(bf2f(vslow[idx]) + ctrl2*bf2f(wfast[idx]));
        }
    } else if (tid < 96){
        int a = (tid-64) >> 4, k = (tid-64) & 15;
        float e = 0.f;
        for (int d = 0; d < 16; ++d){
            float bq = 0.f;
            for (int j = 0; j < 16; ++j) bq += bf2f(basis[a*16+j])*bf2f(wq[j*16+d]);
            e += bq*(bf2f(vslow[d*16+k]) + ctrl2*bf2f(wfast[d*16+k]));
        }
        bex[(33+a)*16+k] = f2bf(0.25f*e);
    }
}

// K4: MFMA continuum+symbiotic, own-row epilogue.
__global__ __launch_bounds__(256) void k4_proc(const u16* xagg, const u16* bex,
    const u16* gateb, const float* scal, u16* xproc, float* wbuf, float* s3)
{
    __shared__ float scal3[4][192];
    __shared__ float part[4][192];
    int tid = threadIdx.x, wave = tid>>6, lane = tid&63;
    int col = lane & 15, quad = lane >> 4;
    short8 z8 = {0,0,0,0,0,0,0,0};
    short8 bc = z8, b2 = z8;
    if (quad < 2){
        bc = *(const short8*)(bex + (16+col)*16 + quad*8);
        b2 = *(const short8*)(bex + (32+col)*16 + quad*8);
    }
    float ctrl0 = scal[1];
    float gb = bf2f(gateb[0]);
    float psum[16], pssq[16];
    #pragma unroll
    for (int i = 0; i < 16; ++i){ psum[i] = 0.f; pssq[i] = 0.f; }
    float pent = 0.f;
    float* sc3 = scal3[wave];
    size_t wbase = ((size_t)blockIdx.x*4 + wave)*1024;
    for (int it2 = 0; it2 < 16; ++it2){
        size_t p0 = wbase + (size_t)it2*64;
        const u16* lbase = xagg + (p0 + col)*16 + quad*8;
        f32x4 cP[4], cS[4];
        #pragma unroll
        for (int g = 0; g < 4; ++g){
            short8 a = z8;
            if (quad < 2) a = *(const short8*)(lbase + g*256);
            f32x4 zc = {0.f,0.f,0.f,0.f};
            cP[g] = MFMA16(a, bc, zc);
            cS[g] = MFMA16(a, b2, zc);
        }
        if (col < 3){
            #pragma unroll
            for (int g = 0; g < 4; ++g)
                #pragma unroll
                for (int r = 0; r < 4; ++r)
                    sc3[(g*16 + quad*4 + r)*3 + col] = cS[g][r];
        }
        float gd  = sc3[lane*3 + 0];
        float e0d = sc3[lane*3 + 1];
        float e1d = sc3[lane*3 + 2];
        float gate_own = ctrl0 / (1.f + __expf(-(gd + gb)));
        float l0 = gate_own*e0d, l1 = gate_own*e1d;
        float w1v = 1.f/(1.f + __expf(l0 - l1));
        float w0v = 1.f - w1v;
        pent += -(w0v*__logf(w0v + 1e-8f) + w1v*__logf(w1v + 1e-8f));
        float2 wv; wv.x = w0v; wv.y = w1v;
        *(float2*)(wbuf + (p0 + lane)*2) = wv;
        u16* sbase = xproc + (p0 + (size_t)quad*4)*16 + col;
        #pragma unroll
        for (int g = 0; g < 4; ++g){
            #pragma unroll
            for (int r = 0; r < 4; ++r){
                float gate = __shfl(gate_own, g*16 + ((lane & 48) >> 2) + r);
                float xp = gate * cP[g][r];
                psum[g*4+r] += xp; pssq[g*4+r] += xp*xp;
                sbase[g*256 + r*16] = f2bf(xp);
            }
        }
    }
    #pragma unroll
    for (int i = 0; i < 16; ++i){
        float a = psum[i], b = pssq[i];
        #pragma unroll
        for (int off = 1; off < 16; off <<= 1){
            a += __shfl_xor(a, off);
            b += __shfl_xor(b, off);
        }
        if (col == 0){
            int n = (i >> 2)*16 + quad*4 + (i & 3);
            part[wave][n]      = a;
            part[wave][64 + n] = b;
        }
    }
    part[wave][128 + lane] = pent;
    __syncthreads();
    if (tid < 192)
        s3[(size_t)blockIdx.x*192 + tid] =
            part[0][tid] + part[1][tid] + part[2][tid] + part[3][tid];
}

// K5: per-node regulator -> infl[64]; entropy(node63), ortho. 1024 thr, 4-way sliced reduce.
__global__ __launch_bounds__(1024) void k5_infl(const u16* basis,
    const u16* w1, const u16* b1, const u16* g, const u16* be, const u16* w2, const u16* b2,
    const float* s3, float* scal, void* dout)
{
    __shared__ double nstp[4*192];
    __shared__ double nst[192];
    int tid = threadIdx.x;
    int c = tid & 255, sl = tid >> 8;
    if (c < 192){
        double a = 0;
        for (int i = sl; i < 512; i += 4) a += (double)s3[(size_t)i*192 + c];
        nstp[sl*192 + c] = a;
    }
    __syncthreads();
    if (tid < 192) nst[tid] = nstp[tid] + nstp[192+tid] + nstp[384+tid] + nstp[576+tid];
    __syncthreads();
    int isfp32 = scal[127] != 0.f;
    if (tid < 64){
        int n = tid;
        double sum = nst[n], ssq = nst[64+n], ent = nst[128+n];
        double Mn = 524288.0;
        float varn = (float)((ssq - sum*sum/Mn)/(Mn - 1.0));
        float entm = (float)(ent / 32768.0);
        float b0[16], b1v[16];
        for (int d = 0; d < 16; ++d){ b0[d] = bf2f(basis[d]); b1v[d] = bf2f(basis[16+d]); }
        float g00=0.f, g01=0.f, g11=0.f;
        for (int d = 0; d < 16; ++d){ g00 += b0[d]*b0[d]; g01 += b0[d]*b1v[d]; g11 += b1v[d]*b1v[d]; }
        float ortho = sqrtf((g00-1.f)*(g00-1.f) + 2.f*g01*g01 + (g11-1.f)*(g11-1.f));
        float sg[3] = {varn, entm, ortho};
        float o[3];
        run_regulator(w1,b1,g,be,w2,b2, sg, 3, o);
        scal[4+n] = o[0];
        if (n == 63){ scal[68] = entm;  store_out(dout, OUT_ENT,   entm,  isfp32); }
        if (n == 0) { scal[69] = ortho; store_out(dout, OUT_ORTHO, ortho, isfp32); }
    }
}

// K6: blend-on-load + MFMA GEMM [B x 1024] @ Wcat^T -> logits, relu h, x_flat stats.
__global__ __launch_bounds__(256) void k6_read(const u16* xproc, const float* wbuf, const u16* wcat,
    const u16* basis, const u16* bread, const float* scal,
    void* dout, float* hbuf, float* s4)
{
    __shared__ float infl_s[64], b0s[16], b1s[16], brd[16];
    __shared__ float red[8];
    int tid = threadIdx.x;
    int isfp32 = scal[127] != 0.f;
    if (tid < 64) infl_s[tid] = scal[4+tid];
    if (tid < 16){
        b0s[tid] = bf2f(basis[tid]);
        b1s[tid] = bf2f(basis[16+tid]);
        brd[tid] = (tid < 10) ? bf2f(bread[tid]) : 0.f;
    }
    __syncthreads();
    int wave = tid>>6, lane = tid&63;
    int m = lane&15, quad = lane>>4;
    int row = blockIdx.x*64 + wave*16 + m;
    const u16* xrow = xproc + (size_t)row*1024;
    f32x4 acc0 = {0.f,0.f,0.f,0.f}, acc1 = {0.f,0.f,0.f,0.f};
    float psum = 0.f, pssq = 0.f;
    for (int kc = 0; kc < 1024; kc += 32){
        int kb = kc + quad*8;
        int n  = kb >> 4;
        int d0 = kb & 15;
        short8 xp = *(const short8*)(xrow + kb);
        float2 wv = *(const float2*)(wbuf + ((size_t)row*64 + n)*2);
        float fi = infl_s[n], om = 1.f - fi;
        short8 af;
        #pragma unroll
        for (int j = 0; j < 8; ++j){
            int d = d0 + j;
            float xf = om*bf2f((u16)xp[j]) + fi*(wv.x*b0s[d] + wv.y*b1s[d]);
            psum += xf; pssq += xf*xf;
            af[j] = (short)f2bf(xf);
        }
        short8 bb0 = *(const short8*)(wcat + m*1024 + kb);
        short8 bb1 = *(const short8*)(wcat + (16+m)*1024 + kb);
        acc0 = MFMA16(af, bb0, acc0);
        acc1 = MFMA16(af, bb1, acc1);
    }
    int rowbase = blockIdx.x*64 + wave*16 + quad*4;
    #pragma unroll
    for (int r = 0; r < 4; ++r){
        int rowg = rowbase + r;
        if (m < 10) store_out(dout, rowg*10 + m, acc0[r] + brd[m], isfp32);
        else        hbuf[rowg*8 + (m-10)] = fmaxf(acc0[r], 0.f);
        if (m < 2)  hbuf[rowg*8 + 6 + m]  = fmaxf(acc1[r], 0.f);
    }
    #pragma unroll
    for (int off = 32; off > 0; off >>= 1){
        psum += __shfl_xor(psum, off);
        pssq += __shfl_xor(pssq, off);
    }
    if (lane == 0){ red[wave] = psum; red[4+wave] = pssq; }
    __syncthreads();
    if (tid == 0){
        s4[blockIdx.x*2]   = red[0]+red[1]+red[2]+red[3];
        s4[blockIdx.x*2+1] = red[4]+red[5]+red[6]+red[7];
    }
}

// K7: gain regulator
__global__ __launch_bounds__(256) void k7_gain(
    const u16* w1, const u16* b1, const u16* g, const u16* be, const u16* w2, const u16* b2,
    const float* s4, float* scal)
{
    __shared__ double sred[4];
    int tid = threadIdx.x;
    double s=0, ss=0;
    for (int i = tid; i < 512; i += 256){ s += (double)s4[i*2]; ss += (double)s4[i*2+1]; }
    double S  = blk_red(s,  sred, tid);
    double SS = blk_red(ss, sred, tid);
    if (tid == 0){
        double M = 33554432.0;
        float sg[2];
        sg[0] = (float)((SS - S*S/M)/(M - 1.0));
        sg[1] = scal[68];
        float o[3];
        run_regulator(w1,b1,g,be,w2,b2, sg, 2, o);
        scal[3] = o[0];
    }
}

// K8: proj = (h @ sc_w2^T) * gain
__global__ __launch_bounds__(256) void k8_proj(const float* hbuf, const u16* scw2,
                                               const float* scal, void* dout)
{
    __shared__ float w2s[32];
    int tid = threadIdx.x;
    int isfp32 = scal[127] != 0.f;
    if (tid < 32) w2s[tid] = bf2f(scw2[tid]);
    __syncthreads();
    int b = blockIdx.x*256 + tid;
    float gain = scal[3];
    const float* h = hbuf + (size_t)b*8;
    float hv[8];
    #pragma unroll
    for (int k = 0; k < 8; ++k) hv[k] = h[k];
    #pragma unroll
    for (int i = 0; i < 4; ++i){
        float o = 0.f;
        #pragma unroll
        for (int k = 0; k < 8; ++k) o += hv[k]*w2s[i*8+k];
        store_out(dout, OUT_PROJ + b*4 + i, o*gain, isfp32);
    }
}

extern "C" void kernel_launch(void* const* d_in, const int* in_sizes, int n_in,
                              void* d_out, int out_size, void* d_ws, size_t ws_size,
                              hipStream_t stream)
{
    if (ws_size < WS_NEEDED) return;

    char* ws = (char*)d_ws;
    float* scal  = (float*)(ws + OFF_SCAL);
    u16*   adjb  = (u16*)  (ws + OFF_ADJ);
    float* beff  = (float*)(ws + OFF_BEFF);
    u16*   weff  = (u16*)  (ws + OFF_WEFF);
    u16*   wcat  = (u16*)  (ws + OFF_WCAT);
    float* s1    = (float*)(ws + OFF_S1);
    float* s2    = (float*)(ws + OFF_S2);
    float* s3    = (float*)(ws + OFF_S3);
    float* s4    = (float*)(ws + OFF_S4);
    float* hbuf  = (float*)(ws + OFF_H);
    float* wbuf  = (float*)(ws + OFF_W01);
    u16*   xagg  = (u16*)  (ws + OFF_XAGG);
    u16*   xproc = (u16*)  (ws + OFF_XPROC);
    u16*   can   = (u16*)  (ws + OFF_CAN);
    u16*   bex   = (u16*)  (ws + OFF_BEX);
    u16*   wembT = (u16*)  (ws + OFF_WET);
    u16*   vw    = (u16*)  (ws + OFF_VW);
    float* vbias = (float*)(ws + OFF_VB);

    static const int sidx[36] = {2,3,4,5,6,7,8,9,10,11,13,15,
        16,17,18,19,20,21, 22,23,24,25,26,27, 28,29,30,31,32,33, 34,35,36,37,38,39};
    static const int scnt[36] = {1024,4096,4096,256,256,16,1,256,32,256,32,10,
        48,16,16,16,48,3, 48,16,16,16,48,3, 48,16,16,16,48,3, 32,16,16,16,48,3};
    SmallTab t;
    const u16* canp[40];
    {
        int off = (int)CAN_SMALL;
        for (int j = 0; j < 36; ++j){
            t.src[j] = d_in[sidx[j]];
            t.cnt[j] = scnt[j];
            t.off[j] = off;
            canp[sidx[j]] = can + off;
            off += (scnt[j] + 7) & ~7;
        }
    }
    canp[0]  = can + CAN_X;
    canp[1]  = can + CAN_WEMB;
    canp[12] = can + CAN_SCW1;
    canp[14] = can + CAN_WREAD;

    const u16* pr_[6]; const u16* cr_[6]; const u16* sr_[6]; const u16* sc_[6];
    for (int i = 0; i < 6; ++i){
        pr_[i] = canp[16+i]; cr_[i] = canp[22+i];
        sr_[i] = canp[28+i]; sc_[i] = canp[34+i];
    }

    kp_probe<<<1,   256, 0, stream>>>((const u16*)d_in[0], scal);
    kc_big  <<<1024,256, 0, stream>>>(d_in[0], d_in[1], d_in[14], d_in[12], can, scal);
    kc_small<<<16,  256, 0, stream>>>(t, can, scal);
    k0_wcat <<<385, 256, 0, stream>>>(canp[14], canp[12], canp[1], canp[5], canp[7],
                 wcat, wembT, bex);
    k1_embed<<<512, 256, 0, stream>>>(canp[0], canp[1], canp[2], s1);
    k2_adj  <<<1,   256, 0, stream>>>(canp[3], canp[4], canp[2],
                 pr_[0],pr_[1],pr_[2],pr_[3],pr_[4],pr_[5], s1, scal, adjb, beff);
    k2b_mfma<<<64,  256, 0, stream>>>(adjb, wembT, weff);
    kvw     <<<260, 256, 0, stream>>>(canp[5], weff, beff, vw, vbias);
    k3_agg  <<<2048,256, 0, stream>>>(canp[0], weff, beff, vw, vbias, xagg, s2);
    k3b_ctrl<<<1,   256, 0, stream>>>(canp[6], canp[5], canp[9], canp[11], canp[10],
                 cr_[0],cr_[1],cr_[2],cr_[3],cr_[4],cr_[5], s2, scal, bex);
    k4_proc <<<512, 256, 0, stream>>>(xagg, bex, canp[8], scal, xproc, wbuf, s3);
    k5_infl <<<1,  1024, 0, stream>>>(canp[10],
                 sr_[0],sr_[1],sr_[2],sr_[3],sr_[4],sr_[5], s3, scal, d_out);
    k6_read <<<512, 256, 0, stream>>>(xproc, wbuf, wcat, canp[10], canp[15], scal,
                 d_out, hbuf, s4);
    k7_gain <<<1,   256, 0, stream>>>(
                 sc_[0],sc_[1],sc_[2],sc_[3],sc_[4],sc_[5], s4, scal);
    k8_proj <<<128, 256, 0, stream>>>(hbuf, canp[13], scal, d_out);
}